// Round 1
// baseline (17111.523 us; speedup 1.0000x reference)
//
#include <hip/hip_runtime.h>
#include <hip/hip_cooperative_groups.h>

namespace cg = cooperative_groups;

#define Bsz 256
#define Tt  512
#define Hh  128

// ws layout (floats):
//   Wt_ih [3][32][512][4]  float4-packed k-major input weights (layer0: only k4<2 valid)
//   Wt_hh [3][32][512][4]  float4-packed k-major recurrent weights
//   bias  [3][512]         bih + bhh
//   hbuf  [2][3][256][128] double-buffered hidden states
#define OFF_WTHH 196608            // 3*128*512
#define OFF_BIAS 393216            // 2*196608
#define OFF_HBUF 394752            // + 3*512
// total used: 591360 floats = 2.37 MB (cbuf removed: cell state lives in registers)

__global__ void prep_kernel(const float* Wih0, const float* Whh0, const float* bih0, const float* bhh0,
                            const float* Wih1, const float* Whh1, const float* bih1, const float* bhh1,
                            const float* Wih2, const float* Whh2, const float* bih2, const float* bhh2,
                            float* ws)
{
    int gid = blockIdx.x * blockDim.x + threadIdx.x;   // 0..1535
    if (gid >= 3 * 512) return;
    int l = gid >> 9, gc = gid & 511;
    const float* Wih = (l == 0) ? Wih0 : (l == 1) ? Wih1 : Wih2;
    const float* Whh = (l == 0) ? Whh0 : (l == 1) ? Whh1 : Whh2;
    const float* bih = (l == 0) ? bih0 : (l == 1) ? bih1 : bih2;
    const float* bhh = (l == 0) ? bhh0 : (l == 1) ? bhh1 : bhh2;
    int Kin = (l == 0) ? 8 : 128;
    float* Wt_ih = ws + (size_t)l * 128 * 512;
    float* Wt_hh = ws + OFF_WTHH + (size_t)l * 128 * 512;
    float* bias  = ws + OFF_BIAS + l * 512;
    // packed layout: element (k, gc) at (k>>2)*2048 + gc*4 + (k&3)
    for (int k = 0; k < Kin; k++) Wt_ih[(k >> 2) * 2048 + gc * 4 + (k & 3)] = Wih[gc * Kin + k];
    for (int k = 0; k < 128; k++) Wt_hh[(k >> 2) * 2048 + gc * 4 + (k & 3)] = Whh[gc * 128 + k];
    bias[gc] = bih[gc] + bhh[gc];
}

// Persistent cooperative kernel. 192 blocks: layer = blockIdx/64 processes
// t = s - layer (software wavefront); grid.sync() between wavefront slots.
// Per layer: 64 tiles = 16 row-tiles(16 rows) x 4 hcol-tiles(32 hcols).
// Thread tile: 4 rows x 2 gate-cols (gates g and g+2) -> 8 accumulators,
// only 4 ds_read_b128 per 4-k iteration (halved vs 8x1 mapping).
__global__ __launch_bounds__(256) void lstm_kernel(const float* __restrict__ x,
                                                   float* __restrict__ ws)
{
    const float* __restrict__ Wt_ih = ws;
    const float* __restrict__ Wt_hh = ws + OFF_WTHH;
    const float* __restrict__ bias  = ws + OFF_BIAS;
    float* __restrict__ hbuf = ws + OFF_HBUF;

    const int layer = blockIdx.x >> 6;
    const int tile  = blockIdx.x & 63;
    const int r0  = (tile & 15) << 4;   // batch rows [r0, r0+16)
    const int hc0 = (tile >> 4) << 5;   // hidden cols [hc0, hc0+32)
    const int tid = threadIdx.x;

    __shared__ float sAin[16][132];
    __shared__ float sArec[16][132];
    __shared__ float sG[16][132];

    // 4 rows x 2 cols mapping: wave-uniform row group, per-lane column
    const int rg = tid >> 6;                               // 0..3 -> rows rg*4..rg*4+3
    const int c2 = tid & 63;                               // sG col for gate-pair A
    const int gcA = ((c2 >> 5) << 7) + hc0 + (c2 & 31);    // gate 0/1 column
    // gcB = gcA + 256 (gate 2/3 column)
    const float bbA = bias[layer * 512 + gcA];
    const float bbB = bias[layer * 512 + gcA + 256];

    const float4* __restrict__ W4ih = (const float4*)(Wt_ih + (size_t)layer * 65536) + gcA;
    const float4* __restrict__ W4hh = (const float4*)(Wt_hh + (size_t)layer * 65536) + gcA;

    // persistent cell state: 2 cells per thread, fixed mapping across all t
    const int cr0 = tid >> 5,         cw0 = tid & 31;      // rows 0..7
    const int cr1 = (tid + 256) >> 5, cw1 = tid & 31;      // rows 8..15
    float creg0 = 0.f, creg1 = 0.f;

    const int Kin4 = (layer == 0) ? 2 : 32;

    cg::grid_group grid = cg::this_grid();

    for (int s = 0; s < Tt + 2; ++s) {
        const int t = s - layer;
        if (t >= 0 && t < Tt) {
            const int prev = (s - 1) & 1, cur = s & 1;

            // ---- stage A tiles into LDS ----
            if (layer == 0) {
                if (tid < 128) {
                    int r = tid >> 3, i = tid & 7;
                    sAin[r][i] = x[((size_t)(r0 + r) * Tt + t) * 8 + i];
                }
            } else {
                const float* hprev_in = hbuf + ((size_t)prev * 3 + (layer - 1)) * Bsz * Hh;
                int e = tid * 8; int r = e >> 7, k = e & 127;
                const float* src = hprev_in + (size_t)(r0 + r) * Hh + k;
                *(float4*)&sAin[r][k]     = *(const float4*)(src);
                *(float4*)&sAin[r][k + 4] = *(const float4*)(src + 4);
            }
            if (t > 0) {
                const float* hprev_rec = hbuf + ((size_t)prev * 3 + layer) * Bsz * Hh;
                int e = tid * 8; int r = e >> 7, k = e & 127;
                const float* src = hprev_rec + (size_t)(r0 + r) * Hh + k;
                *(float4*)&sArec[r][k]     = *(const float4*)(src);
                *(float4*)&sArec[r][k + 4] = *(const float4*)(src + 4);
            }
            __syncthreads();

            // ---- GEMM: 4 rows x 2 gate-cols per thread ----
            float accA[4], accB[4];
#pragma unroll
            for (int j = 0; j < 4; j++) { accA[j] = bbA; accB[j] = bbB; }

            for (int k4 = 0; k4 < Kin4; k4++) {
                float4 wA = W4ih[(size_t)k4 * 512];
                float4 wB = W4ih[(size_t)k4 * 512 + 256];
#pragma unroll
                for (int j = 0; j < 4; j++) {
                    float4 a = *(const float4*)&sAin[rg * 4 + j][k4 * 4];
                    accA[j] += a.x * wA.x + a.y * wA.y + a.z * wA.z + a.w * wA.w;
                    accB[j] += a.x * wB.x + a.y * wB.y + a.z * wB.z + a.w * wB.w;
                }
            }
            if (t > 0) {
#pragma unroll 8
                for (int k4 = 0; k4 < 32; k4++) {
                    float4 wA = W4hh[(size_t)k4 * 512];
                    float4 wB = W4hh[(size_t)k4 * 512 + 256];
#pragma unroll
                    for (int j = 0; j < 4; j++) {
                        float4 a = *(const float4*)&sArec[rg * 4 + j][k4 * 4];
                        accA[j] += a.x * wA.x + a.y * wA.y + a.z * wA.z + a.w * wA.w;
                        accB[j] += a.x * wB.x + a.y * wB.y + a.z * wB.z + a.w * wB.w;
                    }
                }
            }
#pragma unroll
            for (int j = 0; j < 4; j++) {
                sG[rg * 4 + j][c2]      = accA[j];
                sG[rg * 4 + j][c2 + 64] = accB[j];
            }
            __syncthreads();

            // ---- LSTM cell update: 512 cells / block, 2 per thread, c in regs ----
            float* hcur = hbuf + ((size_t)cur * 3 + layer) * Bsz * Hh;
            {
                float gi = sG[cr0][cw0],      gf = sG[cr0][32 + cw0];
                float gg = sG[cr0][64 + cw0], go = sG[cr0][96 + cw0];
                float si = 1.f / (1.f + __expf(-gi));
                float sf = 1.f / (1.f + __expf(-gf));
                float so = 1.f / (1.f + __expf(-go));
                creg0 = sf * creg0 + si * tanhf(gg);
                hcur[(size_t)(r0 + cr0) * Hh + hc0 + cw0] = so * tanhf(creg0);
            }
            {
                float gi = sG[cr1][cw1],      gf = sG[cr1][32 + cw1];
                float gg = sG[cr1][64 + cw1], go = sG[cr1][96 + cw1];
                float si = 1.f / (1.f + __expf(-gi));
                float sf = 1.f / (1.f + __expf(-gf));
                float so = 1.f / (1.f + __expf(-go));
                creg1 = sf * creg1 + si * tanhf(gg);
                hcur[(size_t)(r0 + cr1) * Hh + hc0 + cw1] = so * tanhf(creg1);
            }
        }
        grid.sync();   // all blocks, every slot (idle blocks too)
    }
}

__global__ void fc_kernel(const float* __restrict__ ws, const float* __restrict__ Wfc,
                          const float* __restrict__ bfc, float* __restrict__ out)
{
    // final h of layer2 written at s=513 -> parity 1 -> hbuf[1][2]
    const float* h2 = ws + OFF_HBUF + (size_t)(1 * 3 + 2) * Bsz * Hh;
    int b = threadIdx.x;   // 256 threads
    float a0 = bfc[0], a1 = bfc[1], a2 = bfc[2];
    for (int k = 0; k < 128; k++) {
        float h = h2[b * 128 + k];
        a0 += h * Wfc[0 * 128 + k];
        a1 += h * Wfc[1 * 128 + k];
        a2 += h * Wfc[2 * 128 + k];
    }
    out[b * 3 + 0] = a0;
    out[b * 3 + 1] = a1;
    out[b * 3 + 2] = a2;
}

extern "C" void kernel_launch(void* const* d_in, const int* in_sizes, int n_in,
                              void* d_out, int out_size, void* d_ws, size_t ws_size,
                              hipStream_t stream)
{
    const float* x = (const float*)d_in[0];
    float* ws = (float*)d_ws;

    prep_kernel<<<6, 256, 0, stream>>>(
        (const float*)d_in[1],  (const float*)d_in[2],  (const float*)d_in[3],  (const float*)d_in[4],
        (const float*)d_in[5],  (const float*)d_in[6],  (const float*)d_in[7],  (const float*)d_in[8],
        (const float*)d_in[9],  (const float*)d_in[10], (const float*)d_in[11], (const float*)d_in[12],
        ws);

    void* args[2] = { (void*)&x, (void*)&ws };
    hipLaunchCooperativeKernel((void*)lstm_kernel, dim3(192), dim3(256), args, 0, stream);

    fc_kernel<<<1, 256, 0, stream>>>(ws, (const float*)d_in[13], (const float*)d_in[14], (float*)d_out);
}

// Round 2
// 8730.978 us; speedup vs baseline: 1.9599x; 1.9599x over previous
//
#include <hip/hip_runtime.h>

#define Bsz 256
#define Tt  512
#define Hh  128

// ws layout (floats):
//   Wt_ih [3][32][512][4]  float4-packed k-major input weights (layer0: only k4<2 valid)
//   Wt_hh [3][32][512][4]  float4-packed k-major recurrent weights
//   bias  [3][512]         bih + bhh
//   hbuf  [2][3][256][128] double-buffered hidden states
//   flags [3][16][4] ints  progress flags (last completed slot per block)
#define OFF_WTHH 196608            // 3*128*512
#define OFF_BIAS 393216            // 2*196608
#define OFF_HBUF 394752            // + 3*512
#define OFF_FLAG 591360            // + 2*3*256*128
// total used: 591552 floats = 2.37 MB

__global__ void prep_kernel(const float* Wih0, const float* Whh0, const float* bih0, const float* bhh0,
                            const float* Wih1, const float* Whh1, const float* bih1, const float* bhh1,
                            const float* Wih2, const float* Whh2, const float* bih2, const float* bhh2,
                            float* ws)
{
    int gid = blockIdx.x * blockDim.x + threadIdx.x;   // 0..1535
    if (gid < 192) ((int*)(ws + OFF_FLAG))[gid] = -1;  // init progress flags
    if (gid >= 3 * 512) return;
    int l = gid >> 9, gc = gid & 511;
    const float* Wih = (l == 0) ? Wih0 : (l == 1) ? Wih1 : Wih2;
    const float* Whh = (l == 0) ? Whh0 : (l == 1) ? Whh1 : Whh2;
    const float* bih = (l == 0) ? bih0 : (l == 1) ? bih1 : bih2;
    const float* bhh = (l == 0) ? bhh0 : (l == 1) ? bhh1 : bhh2;
    int Kin = (l == 0) ? 8 : 128;
    float* Wt_ih = ws + (size_t)l * 128 * 512;
    float* Wt_hh = ws + OFF_WTHH + (size_t)l * 128 * 512;
    float* bias  = ws + OFF_BIAS + l * 512;
    // packed layout: element (k, gc) at (k>>2)*2048 + gc*4 + (k&3)
    for (int k = 0; k < Kin; k++) Wt_ih[(k >> 2) * 2048 + gc * 4 + (k & 3)] = Wih[gc * Kin + k];
    for (int k = 0; k < 128; k++) Wt_hh[(k >> 2) * 2048 + gc * 4 + (k & 3)] = Whh[gc * 128 + k];
    bias[gc] = bih[gc] + bhh[gc];
}

// Persistent kernel, 192 blocks (cooperative launch only to guarantee co-residency;
// NO grid.sync). block = (layer, rtile, hctile): layer = blockIdx/64,
// rt = tile&15 (16 batch rows), hct = tile>>4 (32 hidden cols -> 128 gate cols).
// Software wavefront: block (l,·) processes t = s - l; cross-block deps enforced
// by point-to-point agent-scope flags (last completed slot per block).
__global__ __launch_bounds__(256) void lstm_kernel(const float* __restrict__ x,
                                                   float* __restrict__ ws)
{
    const float* __restrict__ Wt_ih = ws;
    const float* __restrict__ Wt_hh = ws + OFF_WTHH;
    const float* __restrict__ bias  = ws + OFF_BIAS;
    float* __restrict__ hbuf = ws + OFF_HBUF;
    int* __restrict__ fl = (int*)(ws + OFF_FLAG);

    const int layer = blockIdx.x >> 6;
    const int tile  = blockIdx.x & 63;
    const int rt  = tile & 15;
    const int hct = tile >> 4;
    const int r0  = rt << 4;            // batch rows [r0, r0+16)
    const int hc0 = hct << 5;           // hidden cols [hc0, hc0+32)
    const int tid = threadIdx.x;

    __shared__ float sAin[16][132];
    __shared__ float sArec[16][132];
    __shared__ float sG[16][132];

    // ---- flag plumbing ----
    int* myflag = fl + (layer * 16 + rt) * 4 + hct;
    int* depp = nullptr;
    int minT = 0;
    if (tid < 12) {
        int g = tid >> 2, h = tid & 3;
        if (g == 0) {                       // own layer (recurrent + own parity)
            depp = fl + (layer * 16 + rt) * 4 + h;  minT = 1;
        } else if (g == 1) {                // upstream layer (input h)
            if (layer > 0) { depp = fl + ((layer - 1) * 16 + rt) * 4 + h; minT = 0; }
        } else {                            // downstream layer (anti-dep on parity)
            if (layer < 2) { depp = fl + ((layer + 1) * 16 + rt) * 4 + h; minT = 2; }
        }
    }

    // 4 rows x 2 cols mapping: wave-uniform row group, per-lane column
    const int rg = tid >> 6;                               // 0..3 -> rows rg*4..rg*4+3
    const int c2 = tid & 63;                               // sG col for gate-pair A
    const int gcA = ((c2 >> 5) << 7) + hc0 + (c2 & 31);    // gate 0/1 column
    const float bbA = bias[layer * 512 + gcA];
    const float bbB = bias[layer * 512 + gcA + 256];

    const float4* __restrict__ W4ih = (const float4*)(Wt_ih + (size_t)layer * 65536) + gcA;
    const float4* __restrict__ W4hh = (const float4*)(Wt_hh + (size_t)layer * 65536) + gcA;

    // persistent cell state: 2 cells per thread, fixed mapping across all t
    const int cr0 = tid >> 5,         cw0 = tid & 31;      // rows 0..7
    const int cr1 = (tid + 256) >> 5, cw1 = tid & 31;      // rows 8..15
    float creg0 = 0.f, creg1 = 0.f;

    const int Kin4 = (layer == 0) ? 2 : 32;

    for (int t = 0; t < Tt; ++t) {
        const int s = t + layer;
        const int prev = (s - 1) & 1, cur = s & 1;

        // ---- wait for producers / readers (point-to-point) ----
        if (depp != nullptr && t >= minT) {
            const int target = s - 1;
            while (__hip_atomic_load(depp, __ATOMIC_RELAXED, __HIP_MEMORY_SCOPE_AGENT) < target)
                __builtin_amdgcn_s_sleep(1);
            (void)__hip_atomic_load(depp, __ATOMIC_ACQUIRE, __HIP_MEMORY_SCOPE_AGENT);
        }
        __syncthreads();   // bar1: deps satisfied for whole block

        // ---- stage A tiles into LDS ----
        if (layer == 0) {
            if (tid < 128) {
                int r = tid >> 3, i = tid & 7;
                sAin[r][i] = x[((size_t)(r0 + r) * Tt + t) * 8 + i];
            }
        } else {
            const float* hprev_in = hbuf + ((size_t)prev * 3 + (layer - 1)) * Bsz * Hh;
            int e = tid * 8; int r = e >> 7, k = e & 127;
            const float* src = hprev_in + (size_t)(r0 + r) * Hh + k;
            *(float4*)&sAin[r][k]     = *(const float4*)(src);
            *(float4*)&sAin[r][k + 4] = *(const float4*)(src + 4);
        }
        if (t > 0) {
            const float* hprev_rec = hbuf + ((size_t)prev * 3 + layer) * Bsz * Hh;
            int e = tid * 8; int r = e >> 7, k = e & 127;
            const float* src = hprev_rec + (size_t)(r0 + r) * Hh + k;
            *(float4*)&sArec[r][k]     = *(const float4*)(src);
            *(float4*)&sArec[r][k + 4] = *(const float4*)(src + 4);
        }
        __syncthreads();   // bar2: staging visible

        // ---- GEMM: 4 rows x 2 gate-cols per thread ----
        float accA[4], accB[4];
#pragma unroll
        for (int j = 0; j < 4; j++) { accA[j] = bbA; accB[j] = bbB; }

        for (int k4 = 0; k4 < Kin4; k4++) {
            float4 wA = W4ih[(size_t)k4 * 512];
            float4 wB = W4ih[(size_t)k4 * 512 + 256];
#pragma unroll
            for (int j = 0; j < 4; j++) {
                float4 a = *(const float4*)&sAin[rg * 4 + j][k4 * 4];
                accA[j] += a.x * wA.x + a.y * wA.y + a.z * wA.z + a.w * wA.w;
                accB[j] += a.x * wB.x + a.y * wB.y + a.z * wB.z + a.w * wB.w;
            }
        }
        if (t > 0) {
#pragma unroll 8
            for (int k4 = 0; k4 < 32; k4++) {
                float4 wA = W4hh[(size_t)k4 * 512];
                float4 wB = W4hh[(size_t)k4 * 512 + 256];
#pragma unroll
                for (int j = 0; j < 4; j++) {
                    float4 a = *(const float4*)&sArec[rg * 4 + j][k4 * 4];
                    accA[j] += a.x * wA.x + a.y * wA.y + a.z * wA.z + a.w * wA.w;
                    accB[j] += a.x * wB.x + a.y * wB.y + a.z * wB.z + a.w * wB.w;
                }
            }
        }
#pragma unroll
        for (int j = 0; j < 4; j++) {
            sG[rg * 4 + j][c2]      = accA[j];
            sG[rg * 4 + j][c2 + 64] = accB[j];
        }
        __syncthreads();   // bar3: sG visible

        // ---- LSTM cell update: 512 cells / block, 2 per thread, c in regs ----
        float* hcur = hbuf + ((size_t)cur * 3 + layer) * Bsz * Hh;
        {
            float gi = sG[cr0][cw0],      gf = sG[cr0][32 + cw0];
            float gg = sG[cr0][64 + cw0], go = sG[cr0][96 + cw0];
            float si = 1.f / (1.f + __expf(-gi));
            float sf = 1.f / (1.f + __expf(-gf));
            float so = 1.f / (1.f + __expf(-go));
            creg0 = sf * creg0 + si * tanhf(gg);
            hcur[(size_t)(r0 + cr0) * Hh + hc0 + cw0] = so * tanhf(creg0);
        }
        {
            float gi = sG[cr1][cw1],      gf = sG[cr1][32 + cw1];
            float gg = sG[cr1][64 + cw1], go = sG[cr1][96 + cw1];
            float si = 1.f / (1.f + __expf(-gi));
            float sf = 1.f / (1.f + __expf(-gf));
            float so = 1.f / (1.f + __expf(-go));
            creg1 = sf * creg1 + si * tanhf(gg);
            hcur[(size_t)(r0 + cr1) * Hh + hc0 + cw1] = so * tanhf(creg1);
        }
        __syncthreads();   // bar4: all h stores drained (vmcnt 0 at barrier)

        // ---- publish progress (release: writes back XCD L2 for cross-XCD readers) ----
        if (tid == 0)
            __hip_atomic_store(myflag, s, __ATOMIC_RELEASE, __HIP_MEMORY_SCOPE_AGENT);
    }
}

__global__ void fc_kernel(const float* __restrict__ ws, const float* __restrict__ Wfc,
                          const float* __restrict__ bfc, float* __restrict__ out)
{
    // final h of layer2 written at s=513 -> parity 1 -> hbuf[1][2]
    const float* h2 = ws + OFF_HBUF + (size_t)(1 * 3 + 2) * Bsz * Hh;
    int b = threadIdx.x;   // 256 threads
    float a0 = bfc[0], a1 = bfc[1], a2 = bfc[2];
    for (int k = 0; k < 128; k++) {
        float h = h2[b * 128 + k];
        a0 += h * Wfc[0 * 128 + k];
        a1 += h * Wfc[1 * 128 + k];
        a2 += h * Wfc[2 * 128 + k];
    }
    out[b * 3 + 0] = a0;
    out[b * 3 + 1] = a1;
    out[b * 3 + 2] = a2;
}

extern "C" void kernel_launch(void* const* d_in, const int* in_sizes, int n_in,
                              void* d_out, int out_size, void* d_ws, size_t ws_size,
                              hipStream_t stream)
{
    const float* x = (const float*)d_in[0];
    float* ws = (float*)d_ws;

    prep_kernel<<<6, 256, 0, stream>>>(
        (const float*)d_in[1],  (const float*)d_in[2],  (const float*)d_in[3],  (const float*)d_in[4],
        (const float*)d_in[5],  (const float*)d_in[6],  (const float*)d_in[7],  (const float*)d_in[8],
        (const float*)d_in[9],  (const float*)d_in[10], (const float*)d_in[11], (const float*)d_in[12],
        ws);

    // cooperative launch solely for the co-residency guarantee (no grid.sync inside)
    void* args[2] = { (void*)&x, (void*)&ws };
    hipLaunchCooperativeKernel((void*)lstm_kernel, dim3(192), dim3(256), args, 0, stream);

    fc_kernel<<<1, 256, 0, stream>>>(ws, (const float*)d_in[13], (const float*)d_in[14], (float*)d_out);
}

// Round 3
// 7080.501 us; speedup vs baseline: 2.4167x; 1.2331x over previous
//
#include <hip/hip_runtime.h>

#define Bsz 256
#define Tt  512
#define Hh  128

// ws layout (floats):
//   Wt_ih [3][32][512][4]  float4-packed k-major input weights (layer0: only k4<2 valid)
//   Wt_hh [3][32][512][4]  float4-packed k-major recurrent weights
//   bias  [3][512]         bih + bhh
//   hbuf  [2][3][256][128] double-buffered hidden states (MALL-coherent sc1 path)
//   flags [3][16][4] ints  progress flags (last completed slot per block)
#define OFF_WTHH 196608            // 3*128*512
#define OFF_BIAS 393216            // 2*196608
#define OFF_HBUF 394752            // + 3*512
#define OFF_FLAG 591360            // + 2*3*256*128
// total used: 591552 floats = 2.37 MB

// ---- MALL-coherent data movement: relaxed agent-scope atomics.
// These compile to per-access coherent global loads/stores (sc0 sc1) with NO
// cache-wide maintenance (no buffer_inv / wbl2), unlike acquire/release.
__device__ __forceinline__ void st_f32_agent(float* p, float v) {
    __hip_atomic_store(p, v, __ATOMIC_RELAXED, __HIP_MEMORY_SCOPE_AGENT);
}
__device__ __forceinline__ float2 ld_f2_agent(const float* p) {
    unsigned long long u = __hip_atomic_load((unsigned long long*)p,
                                             __ATOMIC_RELAXED, __HIP_MEMORY_SCOPE_AGENT);
    float2 r;
    r.x = __uint_as_float((unsigned int)(u & 0xffffffffull));
    r.y = __uint_as_float((unsigned int)(u >> 32));
    return r;
}

__global__ void prep_kernel(const float* Wih0, const float* Whh0, const float* bih0, const float* bhh0,
                            const float* Wih1, const float* Whh1, const float* bih1, const float* bhh1,
                            const float* Wih2, const float* Whh2, const float* bih2, const float* bhh2,
                            float* ws)
{
    int gid = blockIdx.x * blockDim.x + threadIdx.x;   // 0..1535
    if (gid < 192) ((int*)(ws + OFF_FLAG))[gid] = -1;  // init progress flags
    if (gid >= 3 * 512) return;
    int l = gid >> 9, gc = gid & 511;
    const float* Wih = (l == 0) ? Wih0 : (l == 1) ? Wih1 : Wih2;
    const float* Whh = (l == 0) ? Whh0 : (l == 1) ? Whh1 : Whh2;
    const float* bih = (l == 0) ? bih0 : (l == 1) ? bih1 : bih2;
    const float* bhh = (l == 0) ? bhh0 : (l == 1) ? bhh1 : bhh2;
    int Kin = (l == 0) ? 8 : 128;
    float* Wt_ih = ws + (size_t)l * 128 * 512;
    float* Wt_hh = ws + OFF_WTHH + (size_t)l * 128 * 512;
    float* bias  = ws + OFF_BIAS + l * 512;
    // packed layout: element (k, gc) at (k>>2)*2048 + gc*4 + (k&3)
    for (int k = 0; k < Kin; k++) Wt_ih[(k >> 2) * 2048 + gc * 4 + (k & 3)] = Wih[gc * Kin + k];
    for (int k = 0; k < 128; k++) Wt_hh[(k >> 2) * 2048 + gc * 4 + (k & 3)] = Whh[gc * 128 + k];
    bias[gc] = bih[gc] + bhh[gc];
}

// Persistent kernel, 192 blocks (cooperative launch only for co-residency; no grid.sync).
// block = (layer, rtile, hctile). Software wavefront: block (l,·) processes t = s - l.
// Cross-block deps via point-to-point agent-scope flags; h data moves over the
// MALL-coherent sc1 path so no acquire/release cache maintenance is needed.
// Weights/bias/x use normal cached loads and stay L2-resident (never invalidated).
__global__ __launch_bounds__(256) void lstm_kernel(const float* __restrict__ x,
                                                   float* __restrict__ ws)
{
    const float* __restrict__ Wt_ih = ws;
    const float* __restrict__ Wt_hh = ws + OFF_WTHH;
    const float* __restrict__ bias  = ws + OFF_BIAS;
    float* __restrict__ hbuf = ws + OFF_HBUF;
    int* __restrict__ fl = (int*)(ws + OFF_FLAG);

    const int layer = blockIdx.x >> 6;
    const int tile  = blockIdx.x & 63;
    const int rt  = tile & 15;
    const int hct = tile >> 4;
    const int r0  = rt << 4;            // batch rows [r0, r0+16)
    const int hc0 = hct << 5;           // hidden cols [hc0, hc0+32)
    const int tid = threadIdx.x;

    __shared__ float sAin[16][132];
    __shared__ float sArec[16][132];
    __shared__ float sG[16][132];

    // ---- flag plumbing ----
    int* myflag = fl + (layer * 16 + rt) * 4 + hct;
    int* depp = nullptr;
    int minT = 0;
    if (tid < 12) {
        int g = tid >> 2, h = tid & 3;
        if (g == 0) {                       // own layer (recurrent h + own parity anti-dep)
            depp = fl + (layer * 16 + rt) * 4 + h;  minT = 1;
        } else if (g == 1) {                // upstream layer (input h)
            if (layer > 0) { depp = fl + ((layer - 1) * 16 + rt) * 4 + h; minT = 0; }
        } else {                            // downstream layer (anti-dep on parity)
            if (layer < 2) { depp = fl + ((layer + 1) * 16 + rt) * 4 + h; minT = 2; }
        }
    }

    // 4 rows x 2 cols mapping: wave-uniform row group, per-lane column
    const int rg = tid >> 6;                               // 0..3 -> rows rg*4..rg*4+3
    const int c2 = tid & 63;                               // sG col for gate-pair A
    const int gcA = ((c2 >> 5) << 7) + hc0 + (c2 & 31);    // gate 0/1 column
    const float bbA = bias[layer * 512 + gcA];
    const float bbB = bias[layer * 512 + gcA + 256];

    const float4* __restrict__ W4ih = (const float4*)(Wt_ih + (size_t)layer * 65536) + gcA;
    const float4* __restrict__ W4hh = (const float4*)(Wt_hh + (size_t)layer * 65536) + gcA;

    // persistent cell state: 2 cells per thread, fixed mapping across all t
    const int cr0 = tid >> 5,         cw0 = tid & 31;      // rows 0..7
    const int cr1 = (tid + 256) >> 5, cw1 = tid & 31;      // rows 8..15
    float creg0 = 0.f, creg1 = 0.f;

    const int Kin4 = (layer == 0) ? 2 : 32;

    for (int t = 0; t < Tt; ++t) {
        const int s = t + layer;
        const int prev = (s - 1) & 1, cur = s & 1;

        // ---- wait for producers / readers (point-to-point, relaxed polls) ----
        if (depp != nullptr && t >= minT) {
            const int target = s - 1;
            while (__hip_atomic_load(depp, __ATOMIC_RELAXED, __HIP_MEMORY_SCOPE_AGENT) < target)
                __builtin_amdgcn_s_sleep(1);
        }
        __syncthreads();   // bar1: deps satisfied for whole block

        // ---- stage A tiles into LDS (h via MALL-coherent loads) ----
        if (layer == 0) {
            if (tid < 128) {
                int r = tid >> 3, i = tid & 7;
                sAin[r][i] = x[((size_t)(r0 + r) * Tt + t) * 8 + i];
            }
        } else {
            const float* hprev_in = hbuf + ((size_t)prev * 3 + (layer - 1)) * Bsz * Hh;
            int e = tid * 8; int r = e >> 7, k = e & 127;
            const float* src = hprev_in + (size_t)(r0 + r) * Hh + k;
#pragma unroll
            for (int q = 0; q < 4; q++)
                *(float2*)&sAin[r][k + 2 * q] = ld_f2_agent(src + 2 * q);
        }
        if (t > 0) {
            const float* hprev_rec = hbuf + ((size_t)prev * 3 + layer) * Bsz * Hh;
            int e = tid * 8; int r = e >> 7, k = e & 127;
            const float* src = hprev_rec + (size_t)(r0 + r) * Hh + k;
#pragma unroll
            for (int q = 0; q < 4; q++)
                *(float2*)&sArec[r][k + 2 * q] = ld_f2_agent(src + 2 * q);
        }
        __syncthreads();   // bar2: staging visible

        // ---- GEMM: 4 rows x 2 gate-cols per thread ----
        float accA[4], accB[4];
#pragma unroll
        for (int j = 0; j < 4; j++) { accA[j] = bbA; accB[j] = bbB; }

        for (int k4 = 0; k4 < Kin4; k4++) {
            float4 wA = W4ih[(size_t)k4 * 512];
            float4 wB = W4ih[(size_t)k4 * 512 + 256];
#pragma unroll
            for (int j = 0; j < 4; j++) {
                float4 a = *(const float4*)&sAin[rg * 4 + j][k4 * 4];
                accA[j] += a.x * wA.x + a.y * wA.y + a.z * wA.z + a.w * wA.w;
                accB[j] += a.x * wB.x + a.y * wB.y + a.z * wB.z + a.w * wB.w;
            }
        }
        if (t > 0) {
#pragma unroll 8
            for (int k4 = 0; k4 < 32; k4++) {
                float4 wA = W4hh[(size_t)k4 * 512];
                float4 wB = W4hh[(size_t)k4 * 512 + 256];
#pragma unroll
                for (int j = 0; j < 4; j++) {
                    float4 a = *(const float4*)&sArec[rg * 4 + j][k4 * 4];
                    accA[j] += a.x * wA.x + a.y * wA.y + a.z * wA.z + a.w * wA.w;
                    accB[j] += a.x * wB.x + a.y * wB.y + a.z * wB.z + a.w * wB.w;
                }
            }
        }
#pragma unroll
        for (int j = 0; j < 4; j++) {
            sG[rg * 4 + j][c2]      = accA[j];
            sG[rg * 4 + j][c2 + 64] = accB[j];
        }
        __syncthreads();   // bar3: sG visible

        // ---- LSTM cell update: 512 cells / block, 2 per thread, c in regs ----
        float* hcur = hbuf + ((size_t)cur * 3 + layer) * Bsz * Hh;
        {
            float gi = sG[cr0][cw0],      gf = sG[cr0][32 + cw0];
            float gg = sG[cr0][64 + cw0], go = sG[cr0][96 + cw0];
            float si = 1.f / (1.f + __expf(-gi));
            float sf = 1.f / (1.f + __expf(-gf));
            float so = 1.f / (1.f + __expf(-go));
            creg0 = sf * creg0 + si * tanhf(gg);
            st_f32_agent(&hcur[(size_t)(r0 + cr0) * Hh + hc0 + cw0], so * tanhf(creg0));
        }
        {
            float gi = sG[cr1][cw1],      gf = sG[cr1][32 + cw1];
            float gg = sG[cr1][64 + cw1], go = sG[cr1][96 + cw1];
            float si = 1.f / (1.f + __expf(-gi));
            float sf = 1.f / (1.f + __expf(-gf));
            float so = 1.f / (1.f + __expf(-go));
            creg1 = sf * creg1 + si * tanhf(gg);
            st_f32_agent(&hcur[(size_t)(r0 + cr1) * Hh + hc0 + cw1], so * tanhf(creg1));
        }
        __syncthreads();   // bar4: drains vmcnt -> all sc1 h stores at coherence point

        // ---- publish progress (relaxed: data already globally visible) ----
        if (tid == 0)
            __hip_atomic_store(myflag, s, __ATOMIC_RELAXED, __HIP_MEMORY_SCOPE_AGENT);
    }
}

__global__ void fc_kernel(const float* __restrict__ ws, const float* __restrict__ Wfc,
                          const float* __restrict__ bfc, float* __restrict__ out)
{
    // final h of layer2 written at s=513 -> parity 1 -> hbuf[1][2]
    const float* h2 = ws + OFF_HBUF + (size_t)(1 * 3 + 2) * Bsz * Hh;
    int b = threadIdx.x;   // 256 threads
    float a0 = bfc[0], a1 = bfc[1], a2 = bfc[2];
    for (int k = 0; k < 128; k++) {
        float h = h2[b * 128 + k];
        a0 += h * Wfc[0 * 128 + k];
        a1 += h * Wfc[1 * 128 + k];
        a2 += h * Wfc[2 * 128 + k];
    }
    out[b * 3 + 0] = a0;
    out[b * 3 + 1] = a1;
    out[b * 3 + 2] = a2;
}

extern "C" void kernel_launch(void* const* d_in, const int* in_sizes, int n_in,
                              void* d_out, int out_size, void* d_ws, size_t ws_size,
                              hipStream_t stream)
{
    const float* x = (const float*)d_in[0];
    float* ws = (float*)d_ws;

    prep_kernel<<<6, 256, 0, stream>>>(
        (const float*)d_in[1],  (const float*)d_in[2],  (const float*)d_in[3],  (const float*)d_in[4],
        (const float*)d_in[5],  (const float*)d_in[6],  (const float*)d_in[7],  (const float*)d_in[8],
        (const float*)d_in[9],  (const float*)d_in[10], (const float*)d_in[11], (const float*)d_in[12],
        ws);

    // cooperative launch solely for the co-residency guarantee (no grid.sync inside)
    void* args[2] = { (void*)&x, (void*)&ws };
    hipLaunchCooperativeKernel((void*)lstm_kernel, dim3(192), dim3(256), args, 0, stream);

    fc_kernel<<<1, 256, 0, stream>>>(ws, (const float*)d_in[13], (const float*)d_in[14], (float*)d_out);
}

// Round 4
// 3740.403 us; speedup vs baseline: 4.5748x; 1.8930x over previous
//
#include <hip/hip_runtime.h>

#define Bsz 256
#define Tt  512
#define Hh  128

// ws layout (floats):
//   Wt_ih [3][128][512]    k-major plain input weights (zero-filled k>=Kin)
//   Wt_hh [3][128][512]    k-major plain recurrent weights
//   bias  [3][512]         bih + bhh
//   hbuf  [2][3][256][128] double-buffered hidden states (MALL-coherent sc1 path)
//   flags [3][16][4] ints  progress flags (last completed slot per block)
#define OFF_WTHH 196608            // 3*128*512
#define OFF_BIAS 393216            // 2*196608
#define OFF_HBUF 394752            // + 3*512
#define OFF_FLAG 591360            // + 2*3*256*128
// total used: 591552 floats = 2.37 MB

// swizzled A-tile column: k -> (k>>3)*12 + (k&7)
// kg-group bases 48 B apart -> 16 wave-distinct addrs on 2-way-max bank overlap (free),
// 16B-aligned for ds_read_b128.
#define SKG(k) ((((k) >> 3) * 12) + ((k) & 7))

// ---- MALL-coherent data movement: relaxed agent-scope atomics (sc0 sc1 per-access,
// no cache-wide maintenance).
__device__ __forceinline__ void st_f32_agent(float* p, float v) {
    __hip_atomic_store(p, v, __ATOMIC_RELAXED, __HIP_MEMORY_SCOPE_AGENT);
}
__device__ __forceinline__ float2 ld_f2_agent(const float* p) {
    unsigned long long u = __hip_atomic_load((unsigned long long*)p,
                                             __ATOMIC_RELAXED, __HIP_MEMORY_SCOPE_AGENT);
    float2 r;
    r.x = __uint_as_float((unsigned int)(u & 0xffffffffull));
    r.y = __uint_as_float((unsigned int)(u >> 32));
    return r;
}

// VALU-pipe partial-row reduction: v += row_shr(v) steps; lane 15 of each
// 16-lane DPP row ends with the sum of lanes 0..15. bound_ctrl=1 -> 0-fill.
template<int N>
__device__ __forceinline__ float row_shr_add(float v) {
    int s = __builtin_amdgcn_update_dpp(0, __float_as_int(v), 0x110 + N, 0xF, 0xF, true);
    return v + __int_as_float(s);
}
__device__ __forceinline__ float4 red16(float4 s) {
    s.x = row_shr_add<1>(s.x); s.x = row_shr_add<2>(s.x); s.x = row_shr_add<4>(s.x); s.x = row_shr_add<8>(s.x);
    s.y = row_shr_add<1>(s.y); s.y = row_shr_add<2>(s.y); s.y = row_shr_add<4>(s.y); s.y = row_shr_add<8>(s.y);
    s.z = row_shr_add<1>(s.z); s.z = row_shr_add<2>(s.z); s.z = row_shr_add<4>(s.z); s.z = row_shr_add<8>(s.z);
    s.w = row_shr_add<1>(s.w); s.w = row_shr_add<2>(s.w); s.w = row_shr_add<4>(s.w); s.w = row_shr_add<8>(s.w);
    return s;
}

#define FMA4(S, A, W) { S.x = fmaf(A, W.x, S.x); S.y = fmaf(A, W.y, S.y); \
                        S.z = fmaf(A, W.z, S.z); S.w = fmaf(A, W.w, S.w); }

__global__ void prep_kernel(const float* Wih0, const float* Whh0, const float* bih0, const float* bhh0,
                            const float* Wih1, const float* Whh1, const float* bih1, const float* bhh1,
                            const float* Wih2, const float* Whh2, const float* bih2, const float* bhh2,
                            float* ws)
{
    int gid = blockIdx.x * blockDim.x + threadIdx.x;   // 0..1535
    if (gid < 192) ((int*)(ws + OFF_FLAG))[gid] = -1;  // init progress flags
    if (gid >= 3 * 512) return;
    int l = gid >> 9, gc = gid & 511;
    const float* Wih = (l == 0) ? Wih0 : (l == 1) ? Wih1 : Wih2;
    const float* Whh = (l == 0) ? Whh0 : (l == 1) ? Whh1 : Whh2;
    const float* bih = (l == 0) ? bih0 : (l == 1) ? bih1 : bih2;
    const float* bhh = (l == 0) ? bhh0 : (l == 1) ? bhh1 : bhh2;
    int Kin = (l == 0) ? 8 : 128;
    float* Wt_ih = ws + (size_t)l * 128 * 512;
    float* Wt_hh = ws + OFF_WTHH + (size_t)l * 128 * 512;
    float* bias  = ws + OFF_BIAS + l * 512;
    for (int k = 0; k < 128; k++) Wt_ih[k * 512 + gc] = (k < Kin) ? Wih[gc * Kin + k] : 0.f;
    for (int k = 0; k < 128; k++) Wt_hh[k * 512 + gc] = Whh[gc * 128 + k];
    bias[gc] = bih[gc] + bhh[gc];
}

// Persistent kernel, 192 blocks x 512 threads (8 waves -> 2 waves/SIMD).
// block = (layer, rtile, hctile); software wavefront t = s - layer; point-to-point
// agent-scope flags (unchanged from verified r2/r3 protocol).
// Thread (cg=tid>>4, kg=tid&15): holds Wih/Whh[k=kg*8..+8][cols=cg*4..+4] in 64 VGPRs
// (loaded ONCE); per slot computes 16-row x 4-col partials over its 8-k slice,
// DPP row_shr-reduces across the 16 kg lanes, lane kg==15 writes sG.
__global__ __launch_bounds__(512, 2) void lstm_kernel(const float* __restrict__ x,
                                                      float* __restrict__ ws)
{
    const float* __restrict__ bias = ws + OFF_BIAS;
    float* __restrict__ hbuf = ws + OFF_HBUF;
    int* __restrict__ fl = (int*)(ws + OFF_FLAG);

    const int layer = blockIdx.x >> 6;
    const int tile  = blockIdx.x & 63;
    const int rt  = tile & 15;
    const int hct = tile >> 4;
    const int r0  = rt << 4;            // batch rows [r0, r0+16)
    const int hc0 = hct << 5;           // hidden cols [hc0, hc0+32)
    const int tid = threadIdx.x;

    __shared__ float sAin[16][192];
    __shared__ float sArec[16][192];
    __shared__ float sG[16][132];

    // zero-fill sAin (layer0 reads k>=8 against zero weights; must not be NaN garbage)
    for (int i = tid; i < 16 * 192; i += 512) ((float*)sAin)[i] = 0.f;

    // ---- flag plumbing (identical to verified protocol) ----
    int* myflag = fl + (layer * 16 + rt) * 4 + hct;
    int* depp = nullptr;
    int minT = 0;
    if (tid < 12) {
        int g = tid >> 2, h = tid & 3;
        if (g == 0) {                       // own layer (recurrent h + own parity anti-dep)
            depp = fl + (layer * 16 + rt) * 4 + h;  minT = 1;
        } else if (g == 1) {                // upstream layer (input h)
            if (layer > 0) { depp = fl + ((layer - 1) * 16 + rt) * 4 + h; minT = 0; }
        } else {                            // downstream layer (anti-dep on parity)
            if (layer < 2) { depp = fl + ((layer + 1) * 16 + rt) * 4 + h; minT = 2; }
        }
    }

    // ---- thread tile ----
    const int kg = tid & 15;               // k-group (DPP-row lane 0..15)
    const int cg = tid >> 4;               // col-group 0..31
    const int cbase = cg << 2;             // block-local col 0..124
    const int gcb = ((cbase >> 5) << 7) + hc0 + (cbase & 31);   // global gate col (4 consecutive)
    const int ka = kg * 12;                // swizzled A base for this k-slice

    // ---- load weights into registers (once) ----
    const float* Wl_ih = ws + (size_t)layer * 65536;
    const float* Wl_hh = ws + OFF_WTHH + (size_t)layer * 65536;
    float4 wih[8], whh[8];
#pragma unroll
    for (int kk = 0; kk < 8; kk++) {
        int k = kg * 8 + kk;
        wih[kk] = *(const float4*)&Wl_ih[(size_t)k * 512 + gcb];
        whh[kk] = *(const float4*)&Wl_hh[(size_t)k * 512 + gcb];
    }
    float4 bias4 = *(const float4*)&bias[layer * 512 + gcb];
    if (kg != 15) bias4 = make_float4(0.f, 0.f, 0.f, 0.f);   // bias added once per col

    // staging coords: 32 threads/row x 4 floats
    const int sr = tid >> 5;               // 0..15
    const int sk = (tid & 31) << 2;        // 0,4,...,124
    const int skc = SKG(sk);

    // cell-update coords: 1 cell/thread
    const int ur = tid >> 5, uc = tid & 31;
    float creg = 0.f;

    __syncthreads();   // sAin zero-fill visible

    for (int t = 0; t < Tt; ++t) {
        const int s = t + layer;
        const int prev = (s - 1) & 1, cur = s & 1;

        // ---- wait for producers / readers ----
        if (depp != nullptr && t >= minT) {
            const int target = s - 1;
            while (__hip_atomic_load(depp, __ATOMIC_RELAXED, __HIP_MEMORY_SCOPE_AGENT) < target)
                __builtin_amdgcn_s_sleep(1);
        }
        __syncthreads();   // bar1: deps satisfied

        // ---- stage A tiles into LDS (h over sc1 path) ----
        if (layer == 0) {
            if (tid < 128) {
                int r = tid >> 3, i = tid & 7;
                sAin[r][i] = x[((size_t)(r0 + r) * Tt + t) * 8 + i];
            }
        } else {
            const float* src = hbuf + ((size_t)prev * 3 + (layer - 1)) * Bsz * Hh
                             + (size_t)(r0 + sr) * Hh + sk;
            float2 p0 = ld_f2_agent(src);
            float2 p1 = ld_f2_agent(src + 2);
            *(float4*)&sAin[sr][skc] = make_float4(p0.x, p0.y, p1.x, p1.y);
        }
        if (t > 0) {
            const float* src = hbuf + ((size_t)prev * 3 + layer) * Bsz * Hh
                             + (size_t)(r0 + sr) * Hh + sk;
            float2 p0 = ld_f2_agent(src);
            float2 p1 = ld_f2_agent(src + 2);
            *(float4*)&sArec[sr][skc] = make_float4(p0.x, p0.y, p1.x, p1.y);
        }
        __syncthreads();   // bar2: staging visible

        // ---- GEMM: register weights x LDS A-slices ----
#pragma unroll 4
        for (int r = 0; r < 16; r++) {
            float4 sacc = bias4;
            {
                const float* a = &sAin[r][ka];
                float4 a0 = *(const float4*)a;
                float4 a1 = *(const float4*)(a + 4);
                FMA4(sacc, a0.x, wih[0]); FMA4(sacc, a0.y, wih[1]);
                FMA4(sacc, a0.z, wih[2]); FMA4(sacc, a0.w, wih[3]);
                FMA4(sacc, a1.x, wih[4]); FMA4(sacc, a1.y, wih[5]);
                FMA4(sacc, a1.z, wih[6]); FMA4(sacc, a1.w, wih[7]);
            }
            if (t > 0) {
                const float* a = &sArec[r][ka];
                float4 a0 = *(const float4*)a;
                float4 a1 = *(const float4*)(a + 4);
                FMA4(sacc, a0.x, whh[0]); FMA4(sacc, a0.y, whh[1]);
                FMA4(sacc, a0.z, whh[2]); FMA4(sacc, a0.w, whh[3]);
                FMA4(sacc, a1.x, whh[4]); FMA4(sacc, a1.y, whh[5]);
                FMA4(sacc, a1.z, whh[6]); FMA4(sacc, a1.w, whh[7]);
            }
            sacc = red16(sacc);                       // lane kg==15: full sum + bias
            if (kg == 15) *(float4*)&sG[r][cbase] = sacc;
        }
        __syncthreads();   // bar3: sG visible

        // ---- LSTM cell update: 512 cells / block, 1 per thread, c in reg ----
        float* hcur = hbuf + ((size_t)cur * 3 + layer) * Bsz * Hh;
        {
            float gi = sG[ur][uc],      gf = sG[ur][32 + uc];
            float gg = sG[ur][64 + uc], go = sG[ur][96 + uc];
            float si = 1.f / (1.f + __expf(-gi));
            float sf = 1.f / (1.f + __expf(-gf));
            float so = 1.f / (1.f + __expf(-go));
            creg = sf * creg + si * tanhf(gg);
            st_f32_agent(&hcur[(size_t)(r0 + ur) * Hh + hc0 + uc], so * tanhf(creg));
        }
        __syncthreads();   // bar4: all sc1 h stores drained (vmcnt 0)

        // ---- publish progress ----
        if (tid == 0)
            __hip_atomic_store(myflag, s, __ATOMIC_RELAXED, __HIP_MEMORY_SCOPE_AGENT);
    }
}

__global__ void fc_kernel(const float* __restrict__ ws, const float* __restrict__ Wfc,
                          const float* __restrict__ bfc, float* __restrict__ out)
{
    // final h of layer2 written at s=513 -> parity 1 -> hbuf[1][2]
    const float* h2 = ws + OFF_HBUF + (size_t)(1 * 3 + 2) * Bsz * Hh;
    int b = threadIdx.x;   // 256 threads
    float a0 = bfc[0], a1 = bfc[1], a2 = bfc[2];
    for (int k = 0; k < 128; k++) {
        float h = h2[b * 128 + k];
        a0 += h * Wfc[0 * 128 + k];
        a1 += h * Wfc[1 * 128 + k];
        a2 += h * Wfc[2 * 128 + k];
    }
    out[b * 3 + 0] = a0;
    out[b * 3 + 1] = a1;
    out[b * 3 + 2] = a2;
}

extern "C" void kernel_launch(void* const* d_in, const int* in_sizes, int n_in,
                              void* d_out, int out_size, void* d_ws, size_t ws_size,
                              hipStream_t stream)
{
    const float* x = (const float*)d_in[0];
    float* ws = (float*)d_ws;

    prep_kernel<<<6, 256, 0, stream>>>(
        (const float*)d_in[1],  (const float*)d_in[2],  (const float*)d_in[3],  (const float*)d_in[4],
        (const float*)d_in[5],  (const float*)d_in[6],  (const float*)d_in[7],  (const float*)d_in[8],
        (const float*)d_in[9],  (const float*)d_in[10], (const float*)d_in[11], (const float*)d_in[12],
        ws);

    // cooperative launch solely for the co-residency guarantee (no grid.sync inside)
    void* args[2] = { (void*)&x, (void*)&ws };
    hipLaunchCooperativeKernel((void*)lstm_kernel, dim3(192), dim3(512), args, 0, stream);

    fc_kernel<<<1, 256, 0, stream>>>(ws, (const float*)d_in[13], (const float*)d_in[14], (float*)d_out);
}

// Round 5
// 3474.796 us; speedup vs baseline: 4.9245x; 1.0764x over previous
//
#include <hip/hip_runtime.h>

#define Bsz 256
#define Tt  512
#define Hh  128

// ws layout (floats):
//   Wt_ih [3][128][512]    k-major plain input weights (zero-filled k>=Kin)
//   Wt_hh [3][128][512]    k-major plain recurrent weights
//   bias  [3][512]         bih + bhh
//   hbuf  [2][3][256][128] double-buffered hidden states (MALL-coherent sc1 path)
//   flags [3][16][4] ints  progress flags (last completed slot per block)
#define OFF_WTHH 196608            // 3*128*512
#define OFF_BIAS 393216            // 2*196608
#define OFF_HBUF 394752            // + 3*512
#define OFF_FLAG 591360            // + 2*3*256*128
// total used: 591552 floats = 2.37 MB

// swizzled A-tile column: k -> (k>>3)*12 + (k&7); 8-float k-groups at 48 B stride
// -> 16 wave-distinct addrs, 2-way max bank aliasing (free), 16B-aligned b128 reads.
#define SKG(k) ((((k) >> 3) * 12) + ((k) & 7))

// ---- MALL-coherent data movement: relaxed agent-scope atomics (sc0 sc1 per-access,
// no cache-wide maintenance).
__device__ __forceinline__ void st_f32_agent(float* p, float v) {
    __hip_atomic_store(p, v, __ATOMIC_RELAXED, __HIP_MEMORY_SCOPE_AGENT);
}
__device__ __forceinline__ float2 ld_f2_agent(const float* p) {
    unsigned long long u = __hip_atomic_load((unsigned long long*)p,
                                             __ATOMIC_RELAXED, __HIP_MEMORY_SCOPE_AGENT);
    float2 r;
    r.x = __uint_as_float((unsigned int)(u & 0xffffffffull));
    r.y = __uint_as_float((unsigned int)(u >> 32));
    return r;
}

// VALU-pipe partial-row reduction: lane 15 of each 16-lane DPP row ends with the
// sum of lanes 0..15. bound_ctrl=1 -> 0-fill.
template<int N>
__device__ __forceinline__ float row_shr_add(float v) {
    int s = __builtin_amdgcn_update_dpp(0, __float_as_int(v), 0x110 + N, 0xF, 0xF, true);
    return v + __int_as_float(s);
}
__device__ __forceinline__ float4 red16(float4 s) {
    s.x = row_shr_add<1>(s.x); s.x = row_shr_add<2>(s.x); s.x = row_shr_add<4>(s.x); s.x = row_shr_add<8>(s.x);
    s.y = row_shr_add<1>(s.y); s.y = row_shr_add<2>(s.y); s.y = row_shr_add<4>(s.y); s.y = row_shr_add<8>(s.y);
    s.z = row_shr_add<1>(s.z); s.z = row_shr_add<2>(s.z); s.z = row_shr_add<4>(s.z); s.z = row_shr_add<8>(s.z);
    s.w = row_shr_add<1>(s.w); s.w = row_shr_add<2>(s.w); s.w = row_shr_add<4>(s.w); s.w = row_shr_add<8>(s.w);
    return s;
}

#define FMA4(S, A, W) { S.x = fmaf(A, W.x, S.x); S.y = fmaf(A, W.y, S.y); \
                        S.z = fmaf(A, W.z, S.z); S.w = fmaf(A, W.w, S.w); }

__global__ void prep_kernel(const float* Wih0, const float* Whh0, const float* bih0, const float* bhh0,
                            const float* Wih1, const float* Whh1, const float* bih1, const float* bhh1,
                            const float* Wih2, const float* Whh2, const float* bih2, const float* bhh2,
                            float* ws)
{
    int gid = blockIdx.x * blockDim.x + threadIdx.x;   // 0..1535
    if (gid < 192) ((int*)(ws + OFF_FLAG))[gid] = -1;  // init progress flags
    if (gid >= 3 * 512) return;
    int l = gid >> 9, gc = gid & 511;
    const float* Wih = (l == 0) ? Wih0 : (l == 1) ? Wih1 : Wih2;
    const float* Whh = (l == 0) ? Whh0 : (l == 1) ? Whh1 : Whh2;
    const float* bih = (l == 0) ? bih0 : (l == 1) ? bih1 : bih2;
    const float* bhh = (l == 0) ? bhh0 : (l == 1) ? bhh1 : bhh2;
    int Kin = (l == 0) ? 8 : 128;
    float* Wt_ih = ws + (size_t)l * 128 * 512;
    float* Wt_hh = ws + OFF_WTHH + (size_t)l * 128 * 512;
    float* bias  = ws + OFF_BIAS + l * 512;
    for (int k = 0; k < 128; k++) Wt_ih[k * 512 + gc] = (k < Kin) ? Wih[gc * Kin + k] : 0.f;
    for (int k = 0; k < 128; k++) Wt_hh[k * 512 + gc] = Whh[gc * 128 + k];
    bias[gc] = bih[gc] + bhh[gc];
}

// Persistent kernel, 192 blocks x 512 threads (8 waves -> 2 waves/SIMD).
// block = (layer, rtile, hctile); software wavefront t = s - layer; point-to-point
// agent-scope flags (verified r2-r4 protocol).
// Thread (kg=tid&15, rg=(tid>>4)&1, cg=tid>>5): holds Wih/Whh[k=kg*8..+8][cols=cg*8..+8]
// in 128 VGPRs (loaded ONCE); per slot computes 8 rows (rg half) x 8 cols over its
// 8-k slice, DPP row_shr-reduces across the 16 kg lanes, lane kg==15 writes sG.
// vs r4: same FMA count & identical reduction tree, but ds_read_b128 per thread
// halves (64 -> 32) -> DS pipe 2.56 -> 1.28 us/slot.
__global__ __launch_bounds__(512, 2) void lstm_kernel(const float* __restrict__ x,
                                                      float* __restrict__ ws)
{
    const float* __restrict__ bias = ws + OFF_BIAS;
    float* __restrict__ hbuf = ws + OFF_HBUF;
    int* __restrict__ fl = (int*)(ws + OFF_FLAG);

    const int layer = blockIdx.x >> 6;
    const int tile  = blockIdx.x & 63;
    const int rt  = tile & 15;
    const int hct = tile >> 4;
    const int r0  = rt << 4;            // batch rows [r0, r0+16)
    const int hc0 = hct << 5;           // hidden cols [hc0, hc0+32)
    const int tid = threadIdx.x;

    __shared__ float sAin[16][192];
    __shared__ float sArec[16][192];
    __shared__ float sG[16][132];

    // zero-fill sAin (layer0 reads k>=8 against zero weights; must not be garbage)
    for (int i = tid; i < 16 * 192; i += 512) ((float*)sAin)[i] = 0.f;

    // ---- flag plumbing (identical to verified protocol) ----
    int* myflag = fl + (layer * 16 + rt) * 4 + hct;
    int* depp = nullptr;
    int minT = 0;
    if (tid < 12) {
        int g = tid >> 2, h = tid & 3;
        if (g == 0) {                       // own layer (recurrent h + own parity anti-dep)
            depp = fl + (layer * 16 + rt) * 4 + h;  minT = 1;
        } else if (g == 1) {                // upstream layer (input h)
            if (layer > 0) { depp = fl + ((layer - 1) * 16 + rt) * 4 + h; minT = 0; }
        } else {                            // downstream layer (anti-dep on parity)
            if (layer < 2) { depp = fl + ((layer + 1) * 16 + rt) * 4 + h; minT = 2; }
        }
    }

    // ---- thread tile ----
    const int kg = tid & 15;               // k-group (DPP-row lane 0..15)
    const int rg = (tid >> 4) & 1;         // row half: rows rg*8 .. rg*8+7
    const int cg = tid >> 5;               // col-group 0..15
    const int cbase = cg << 3;             // block-local col 0..120 (8 cols, same gate)
    const int gcb = ((cbase >> 5) << 7) + hc0 + (cbase & 31);   // global gate col
    const int ka = kg * 12;                // swizzled A base for this k-slice

    // ---- load weights into registers (once): 32 float4 = 128 VGPR ----
    const float* Wl_ih = ws + (size_t)layer * 65536;
    const float* Wl_hh = ws + OFF_WTHH + (size_t)layer * 65536;
    float4 wihA[8], wihB[8], whhA[8], whhB[8];
#pragma unroll
    for (int kk = 0; kk < 8; kk++) {
        int k = kg * 8 + kk;
        wihA[kk] = *(const float4*)&Wl_ih[(size_t)k * 512 + gcb];
        wihB[kk] = *(const float4*)&Wl_ih[(size_t)k * 512 + gcb + 4];
        whhA[kk] = *(const float4*)&Wl_hh[(size_t)k * 512 + gcb];
        whhB[kk] = *(const float4*)&Wl_hh[(size_t)k * 512 + gcb + 4];
    }
    float4 bias4a = *(const float4*)&bias[layer * 512 + gcb];
    float4 bias4b = *(const float4*)&bias[layer * 512 + gcb + 4];
    if (kg != 15) {   // bias added exactly once per col (at the reduction root lane)
        bias4a = make_float4(0.f, 0.f, 0.f, 0.f);
        bias4b = make_float4(0.f, 0.f, 0.f, 0.f);
    }

    // staging coords: 32 threads/row x 4 floats
    const int sr = tid >> 5;               // 0..15
    const int sk = (tid & 31) << 2;        // 0,4,...,124
    const int skc = SKG(sk);

    // cell-update coords: 1 cell/thread
    const int ur = tid >> 5, uc = tid & 31;
    float creg = 0.f;

    __syncthreads();   // sAin zero-fill visible

    for (int t = 0; t < Tt; ++t) {
        const int s = t + layer;
        const int prev = (s - 1) & 1, cur = s & 1;

        // ---- wait for producers / readers (tight relaxed poll, no sleep) ----
        if (depp != nullptr && t >= minT) {
            const int target = s - 1;
            while (__hip_atomic_load(depp, __ATOMIC_RELAXED, __HIP_MEMORY_SCOPE_AGENT) < target)
                ;
        }
        __syncthreads();   // bar1: deps satisfied

        // ---- stage A tiles into LDS (h over sc1 path) ----
        if (layer == 0) {
            if (tid < 128) {
                int r = tid >> 3, i = tid & 7;
                sAin[r][i] = x[((size_t)(r0 + r) * Tt + t) * 8 + i];
            }
        } else {
            const float* src = hbuf + ((size_t)prev * 3 + (layer - 1)) * Bsz * Hh
                             + (size_t)(r0 + sr) * Hh + sk;
            float2 p0 = ld_f2_agent(src);
            float2 p1 = ld_f2_agent(src + 2);
            *(float4*)&sAin[sr][skc] = make_float4(p0.x, p0.y, p1.x, p1.y);
        }
        if (t > 0) {
            const float* src = hbuf + ((size_t)prev * 3 + layer) * Bsz * Hh
                             + (size_t)(r0 + sr) * Hh + sk;
            float2 p0 = ld_f2_agent(src);
            float2 p1 = ld_f2_agent(src + 2);
            *(float4*)&sArec[sr][skc] = make_float4(p0.x, p0.y, p1.x, p1.y);
        }
        __syncthreads();   // bar2: staging visible

        // ---- GEMM: register weights x LDS A-slices (8 rows x 8 cols / thread) ----
#pragma unroll
        for (int j = 0; j < 8; j++) {
            const int r = rg * 8 + j;
            float4 acc0 = bias4a, acc1 = bias4b;
            {
                float4 a0 = *(const float4*)&sAin[r][ka];
                float4 a1 = *(const float4*)&sAin[r][ka + 4];
                FMA4(acc0, a0.x, wihA[0]); FMA4(acc1, a0.x, wihB[0]);
                FMA4(acc0, a0.y, wihA[1]); FMA4(acc1, a0.y, wihB[1]);
                FMA4(acc0, a0.z, wihA[2]); FMA4(acc1, a0.z, wihB[2]);
                FMA4(acc0, a0.w, wihA[3]); FMA4(acc1, a0.w, wihB[3]);
                FMA4(acc0, a1.x, wihA[4]); FMA4(acc1, a1.x, wihB[4]);
                FMA4(acc0, a1.y, wihA[5]); FMA4(acc1, a1.y, wihB[5]);
                FMA4(acc0, a1.z, wihA[6]); FMA4(acc1, a1.z, wihB[6]);
                FMA4(acc0, a1.w, wihA[7]); FMA4(acc1, a1.w, wihB[7]);
            }
            if (t > 0) {
                float4 b0 = *(const float4*)&sArec[r][ka];
                float4 b1 = *(const float4*)&sArec[r][ka + 4];
                FMA4(acc0, b0.x, whhA[0]); FMA4(acc1, b0.x, whhB[0]);
                FMA4(acc0, b0.y, whhA[1]); FMA4(acc1, b0.y, whhB[1]);
                FMA4(acc0, b0.z, whhA[2]); FMA4(acc1, b0.z, whhB[2]);
                FMA4(acc0, b0.w, whhA[3]); FMA4(acc1, b0.w, whhB[3]);
                FMA4(acc0, b1.x, whhA[4]); FMA4(acc1, b1.x, whhB[4]);
                FMA4(acc0, b1.y, whhA[5]); FMA4(acc1, b1.y, whhB[5]);
                FMA4(acc0, b1.z, whhA[6]); FMA4(acc1, b1.z, whhB[6]);
                FMA4(acc0, b1.w, whhA[7]); FMA4(acc1, b1.w, whhB[7]);
            }
            acc0 = red16(acc0);            // lane kg==15: full sum + bias
            acc1 = red16(acc1);
            if (kg == 15) {
                *(float4*)&sG[r][cbase]     = acc0;
                *(float4*)&sG[r][cbase + 4] = acc1;
            }
        }
        __syncthreads();   // bar3: sG visible

        // ---- LSTM cell update: 512 cells / block, 1 per thread, c in reg ----
        float* hcur = hbuf + ((size_t)cur * 3 + layer) * Bsz * Hh;
        {
            float gi = sG[ur][uc],      gf = sG[ur][32 + uc];
            float gg = sG[ur][64 + uc], go = sG[ur][96 + uc];
            float si = 1.f / (1.f + __expf(-gi));
            float sf = 1.f / (1.f + __expf(-gf));
            float so = 1.f / (1.f + __expf(-go));
            creg = sf * creg + si * tanhf(gg);
            st_f32_agent(&hcur[(size_t)(r0 + ur) * Hh + hc0 + uc], so * tanhf(creg));
        }
        __syncthreads();   // bar4: all sc1 h stores drained (vmcnt 0)

        // ---- publish progress ----
        if (tid == 0)
            __hip_atomic_store(myflag, s, __ATOMIC_RELAXED, __HIP_MEMORY_SCOPE_AGENT);
    }
}

__global__ void fc_kernel(const float* __restrict__ ws, const float* __restrict__ Wfc,
                          const float* __restrict__ bfc, float* __restrict__ out)
{
    // final h of layer2 written at s=513 -> parity 1 -> hbuf[1][2]
    const float* h2 = ws + OFF_HBUF + (size_t)(1 * 3 + 2) * Bsz * Hh;
    int b = threadIdx.x;   // 256 threads
    float a0 = bfc[0], a1 = bfc[1], a2 = bfc[2];
    for (int k = 0; k < 128; k++) {
        float h = h2[b * 128 + k];
        a0 += h * Wfc[0 * 128 + k];
        a1 += h * Wfc[1 * 128 + k];
        a2 += h * Wfc[2 * 128 + k];
    }
    out[b * 3 + 0] = a0;
    out[b * 3 + 1] = a1;
    out[b * 3 + 2] = a2;
}

extern "C" void kernel_launch(void* const* d_in, const int* in_sizes, int n_in,
                              void* d_out, int out_size, void* d_ws, size_t ws_size,
                              hipStream_t stream)
{
    const float* x = (const float*)d_in[0];
    float* ws = (float*)d_ws;

    prep_kernel<<<6, 256, 0, stream>>>(
        (const float*)d_in[1],  (const float*)d_in[2],  (const float*)d_in[3],  (const float*)d_in[4],
        (const float*)d_in[5],  (const float*)d_in[6],  (const float*)d_in[7],  (const float*)d_in[8],
        (const float*)d_in[9],  (const float*)d_in[10], (const float*)d_in[11], (const float*)d_in[12],
        ws);

    // cooperative launch solely for the co-residency guarantee (no grid.sync inside)
    void* args[2] = { (void*)&x, (void*)&ws };
    hipLaunchCooperativeKernel((void*)lstm_kernel, dim3(192), dim3(512), args, 0, stream);

    fc_kernel<<<1, 256, 0, stream>>>(ws, (const float*)d_in[13], (const float*)d_in[14], (float*)d_out);
}

// Round 6
// 3235.829 us; speedup vs baseline: 5.2881x; 1.0739x over previous
//
#include <hip/hip_runtime.h>

#define Bsz 256
#define Tt  512
#define Hh  128

// ws layout (floats):
//   Wt_ih [3][128][512]    k-major plain input weights (zero-filled k>=Kin)
//   Wt_hh [3][128][512]    k-major plain recurrent weights
//   bias  [3][512]         bih + bhh
//   hbuf  [4][3][256][128] 4-deep buffered hidden states (MALL-coherent sc1 path)
//   flags [3][16][4] x 32  progress flags, one per 128B line (MALL hot-line fix)
#define OFF_WTHH 196608            // 3*128*512
#define OFF_BIAS 393216            // 2*196608
#define OFF_HBUF 394752            // + 3*512
#define OFF_FLAG 787968            // + 4*3*256*128
#define FLAG_N   6144              // 192 flags * 32 ints (128B stride)
// total used: 794112 floats = 3.18 MB

// swizzled A-tile column: k -> (k>>3)*12 + (k&7); 8-float k-groups at 48 B stride
// -> 16 wave-distinct addrs, 2-way max bank aliasing (free), 16B-aligned b128 reads.
#define SKG(k) ((((k) >> 3) * 12) + ((k) & 7))

// ---- MALL-coherent data movement: relaxed agent-scope atomics (sc0 sc1 per-access,
// no cache-wide maintenance).
__device__ __forceinline__ void st_f32_agent(float* p, float v) {
    __hip_atomic_store(p, v, __ATOMIC_RELAXED, __HIP_MEMORY_SCOPE_AGENT);
}
__device__ __forceinline__ float2 ld_f2_agent(const float* p) {
    unsigned long long u = __hip_atomic_load((unsigned long long*)p,
                                             __ATOMIC_RELAXED, __HIP_MEMORY_SCOPE_AGENT);
    float2 r;
    r.x = __uint_as_float((unsigned int)(u & 0xffffffffull));
    r.y = __uint_as_float((unsigned int)(u >> 32));
    return r;
}

// VALU-pipe partial-row reduction: lane 15 of each 16-lane DPP row ends with the
// sum of lanes 0..15. bound_ctrl=1 -> 0-fill.
template<int N>
__device__ __forceinline__ float row_shr_add(float v) {
    int s = __builtin_amdgcn_update_dpp(0, __float_as_int(v), 0x110 + N, 0xF, 0xF, true);
    return v + __int_as_float(s);
}
__device__ __forceinline__ float4 red16(float4 s) {
    s.x = row_shr_add<1>(s.x); s.x = row_shr_add<2>(s.x); s.x = row_shr_add<4>(s.x); s.x = row_shr_add<8>(s.x);
    s.y = row_shr_add<1>(s.y); s.y = row_shr_add<2>(s.y); s.y = row_shr_add<4>(s.y); s.y = row_shr_add<8>(s.y);
    s.z = row_shr_add<1>(s.z); s.z = row_shr_add<2>(s.z); s.z = row_shr_add<4>(s.z); s.z = row_shr_add<8>(s.z);
    s.w = row_shr_add<1>(s.w); s.w = row_shr_add<2>(s.w); s.w = row_shr_add<4>(s.w); s.w = row_shr_add<8>(s.w);
    return s;
}

#define FMA4(S, A, W) { S.x = fmaf(A, W.x, S.x); S.y = fmaf(A, W.y, S.y); \
                        S.z = fmaf(A, W.z, S.z); S.w = fmaf(A, W.w, S.w); }

__global__ void prep_kernel(const float* Wih0, const float* Whh0, const float* bih0, const float* bhh0,
                            const float* Wih1, const float* Whh1, const float* bih1, const float* bhh1,
                            const float* Wih2, const float* Whh2, const float* bih2, const float* bhh2,
                            float* ws)
{
    int gid = blockIdx.x * blockDim.x + threadIdx.x;   // 0..1535
    for (int i = gid; i < FLAG_N; i += 1536)
        ((int*)(ws + OFF_FLAG))[i] = -1;               // init padded progress flags
    if (gid >= 3 * 512) return;
    int l = gid >> 9, gc = gid & 511;
    const float* Wih = (l == 0) ? Wih0 : (l == 1) ? Wih1 : Wih2;
    const float* Whh = (l == 0) ? Whh0 : (l == 1) ? Whh1 : Whh2;
    const float* bih = (l == 0) ? bih0 : (l == 1) ? bih1 : bih2;
    const float* bhh = (l == 0) ? bhh0 : (l == 1) ? bhh1 : bhh2;
    int Kin = (l == 0) ? 8 : 128;
    float* Wt_ih = ws + (size_t)l * 128 * 512;
    float* Wt_hh = ws + OFF_WTHH + (size_t)l * 128 * 512;
    float* bias  = ws + OFF_BIAS + l * 512;
    for (int k = 0; k < 128; k++) Wt_ih[k * 512 + gc] = (k < Kin) ? Wih[gc * Kin + k] : 0.f;
    for (int k = 0; k < 128; k++) Wt_hh[k * 512 + gc] = Whh[gc * 128 + k];
    bias[gc] = bih[gc] + bhh[gc];
}

// Persistent kernel, 192 blocks x 512 threads (8 waves -> 2 waves/SIMD).
// block = (layer, rtile, hctile); software wavefront t = s - layer; point-to-point
// agent-scope flags (verified r2-r5 protocol).
// vs r5: hbuf depth 4 (anti-dep target s-3 -> backward layer-coupling off the
// critical cycle) and 128B-padded flags (each poll hits its own MALL line).
__global__ __launch_bounds__(512, 2) void lstm_kernel(const float* __restrict__ x,
                                                      float* __restrict__ ws)
{
    const float* __restrict__ bias = ws + OFF_BIAS;
    float* __restrict__ hbuf = ws + OFF_HBUF;
    int* __restrict__ fl = (int*)(ws + OFF_FLAG);

    const int layer = blockIdx.x >> 6;
    const int tile  = blockIdx.x & 63;
    const int rt  = tile & 15;
    const int hct = tile >> 4;
    const int r0  = rt << 4;            // batch rows [r0, r0+16)
    const int hc0 = hct << 5;           // hidden cols [hc0, hc0+32)
    const int tid = threadIdx.x;

    __shared__ float sAin[16][192];
    __shared__ float sArec[16][192];
    __shared__ float sG[16][132];

    // zero-fill sAin (layer0 reads k>=8 against zero weights; must not be garbage)
    for (int i = tid; i < 16 * 192; i += 512) ((float*)sAin)[i] = 0.f;

    // ---- flag plumbing (padded: flag index * 32 = one 128B line each) ----
    int* myflag = fl + ((layer * 16 + rt) * 4 + hct) * 32;
    int* depp = nullptr;
    int minT = 0;
    int tsub = 1;                          // wait while flag < s - tsub
    if (tid < 12) {
        int g = tid >> 2, h = tid & 3;
        if (g == 0) {                       // own layer (recurrent h), target s-1
            depp = fl + ((layer * 16 + rt) * 4 + h) * 32;  minT = 1;  tsub = 1;
        } else if (g == 1) {                // upstream layer (input h), target s-1
            if (layer > 0) { depp = fl + (((layer - 1) * 16 + rt) * 4 + h) * 32; minT = 0; tsub = 1; }
        } else {                            // downstream layer (anti-dep), target s-3 (depth-4)
            if (layer < 2) { depp = fl + (((layer + 1) * 16 + rt) * 4 + h) * 32; minT = 3 - layer; tsub = 3; }
        }
    }

    // ---- thread tile ----
    const int kg = tid & 15;               // k-group (DPP-row lane 0..15)
    const int rg = (tid >> 4) & 1;         // row half: rows rg*8 .. rg*8+7
    const int cg = tid >> 5;               // col-group 0..15
    const int cbase = cg << 3;             // block-local col 0..120 (8 cols, same gate)
    const int gcb = ((cbase >> 5) << 7) + hc0 + (cbase & 31);   // global gate col
    const int ka = kg * 12;                // swizzled A base for this k-slice

    // ---- load weights into registers (once): 32 float4 = 128 VGPR ----
    const float* Wl_ih = ws + (size_t)layer * 65536;
    const float* Wl_hh = ws + OFF_WTHH + (size_t)layer * 65536;
    float4 wihA[8], wihB[8], whhA[8], whhB[8];
#pragma unroll
    for (int kk = 0; kk < 8; kk++) {
        int k = kg * 8 + kk;
        wihA[kk] = *(const float4*)&Wl_ih[(size_t)k * 512 + gcb];
        wihB[kk] = *(const float4*)&Wl_ih[(size_t)k * 512 + gcb + 4];
        whhA[kk] = *(const float4*)&Wl_hh[(size_t)k * 512 + gcb];
        whhB[kk] = *(const float4*)&Wl_hh[(size_t)k * 512 + gcb + 4];
    }
    float4 bias4a = *(const float4*)&bias[layer * 512 + gcb];
    float4 bias4b = *(const float4*)&bias[layer * 512 + gcb + 4];
    if (kg != 15) {   // bias added exactly once per col (at the reduction root lane)
        bias4a = make_float4(0.f, 0.f, 0.f, 0.f);
        bias4b = make_float4(0.f, 0.f, 0.f, 0.f);
    }

    // staging coords: 32 threads/row x 4 floats
    const int sr = tid >> 5;               // 0..15
    const int sk = (tid & 31) << 2;        // 0,4,...,124
    const int skc = SKG(sk);

    // cell-update coords: 1 cell/thread
    const int ur = tid >> 5, uc = tid & 31;
    float creg = 0.f;

    __syncthreads();   // sAin zero-fill visible

    for (int t = 0; t < Tt; ++t) {
        const int s = t + layer;
        const int prev = (s - 1) & 3, cur = s & 3;   // depth-4 buffering

        // ---- wait for producers / readers (tight relaxed poll, padded lines) ----
        if (depp != nullptr && t >= minT) {
            const int target = s - tsub;
            while (__hip_atomic_load(depp, __ATOMIC_RELAXED, __HIP_MEMORY_SCOPE_AGENT) < target)
                ;
        }
        __syncthreads();   // bar1: deps satisfied

        // ---- stage A tiles into LDS (h over sc1 path) ----
        if (layer == 0) {
            if (tid < 128) {
                int r = tid >> 3, i = tid & 7;
                sAin[r][i] = x[((size_t)(r0 + r) * Tt + t) * 8 + i];
            }
        } else {
            const float* src = hbuf + ((size_t)prev * 3 + (layer - 1)) * Bsz * Hh
                             + (size_t)(r0 + sr) * Hh + sk;
            float2 p0 = ld_f2_agent(src);
            float2 p1 = ld_f2_agent(src + 2);
            *(float4*)&sAin[sr][skc] = make_float4(p0.x, p0.y, p1.x, p1.y);
        }
        if (t > 0) {
            const float* src = hbuf + ((size_t)prev * 3 + layer) * Bsz * Hh
                             + (size_t)(r0 + sr) * Hh + sk;
            float2 p0 = ld_f2_agent(src);
            float2 p1 = ld_f2_agent(src + 2);
            *(float4*)&sArec[sr][skc] = make_float4(p0.x, p0.y, p1.x, p1.y);
        }
        __syncthreads();   // bar2: staging visible

        // ---- GEMM: register weights x LDS A-slices (8 rows x 8 cols / thread) ----
#pragma unroll
        for (int j = 0; j < 8; j++) {
            const int r = rg * 8 + j;
            float4 acc0 = bias4a, acc1 = bias4b;
            {
                float4 a0 = *(const float4*)&sAin[r][ka];
                float4 a1 = *(const float4*)&sAin[r][ka + 4];
                FMA4(acc0, a0.x, wihA[0]); FMA4(acc1, a0.x, wihB[0]);
                FMA4(acc0, a0.y, wihA[1]); FMA4(acc1, a0.y, wihB[1]);
                FMA4(acc0, a0.z, wihA[2]); FMA4(acc1, a0.z, wihB[2]);
                FMA4(acc0, a0.w, wihA[3]); FMA4(acc1, a0.w, wihB[3]);
                FMA4(acc0, a1.x, wihA[4]); FMA4(acc1, a1.x, wihB[4]);
                FMA4(acc0, a1.y, wihA[5]); FMA4(acc1, a1.y, wihB[5]);
                FMA4(acc0, a1.z, wihA[6]); FMA4(acc1, a1.z, wihB[6]);
                FMA4(acc0, a1.w, wihA[7]); FMA4(acc1, a1.w, wihB[7]);
            }
            if (t > 0) {
                float4 b0 = *(const float4*)&sArec[r][ka];
                float4 b1 = *(const float4*)&sArec[r][ka + 4];
                FMA4(acc0, b0.x, whhA[0]); FMA4(acc1, b0.x, whhB[0]);
                FMA4(acc0, b0.y, whhA[1]); FMA4(acc1, b0.y, whhB[1]);
                FMA4(acc0, b0.z, whhA[2]); FMA4(acc1, b0.z, whhB[2]);
                FMA4(acc0, b0.w, whhA[3]); FMA4(acc1, b0.w, whhB[3]);
                FMA4(acc0, b1.x, whhA[4]); FMA4(acc1, b1.x, whhB[4]);
                FMA4(acc0, b1.y, whhA[5]); FMA4(acc1, b1.y, whhB[5]);
                FMA4(acc0, b1.z, whhA[6]); FMA4(acc1, b1.z, whhB[6]);
                FMA4(acc0, b1.w, whhA[7]); FMA4(acc1, b1.w, whhB[7]);
            }
            acc0 = red16(acc0);            // lane kg==15: full sum + bias
            acc1 = red16(acc1);
            if (kg == 15) {
                *(float4*)&sG[r][cbase]     = acc0;
                *(float4*)&sG[r][cbase + 4] = acc1;
            }
        }
        __syncthreads();   // bar3: sG visible

        // ---- LSTM cell update: 512 cells / block, 1 per thread, c in reg ----
        float* hcur = hbuf + ((size_t)cur * 3 + layer) * Bsz * Hh;
        {
            float gi = sG[ur][uc],      gf = sG[ur][32 + uc];
            float gg = sG[ur][64 + uc], go = sG[ur][96 + uc];
            float si = 1.f / (1.f + __expf(-gi));
            float sf = 1.f / (1.f + __expf(-gf));
            float so = 1.f / (1.f + __expf(-go));
            creg = sf * creg + si * tanhf(gg);
            st_f32_agent(&hcur[(size_t)(r0 + ur) * Hh + hc0 + uc], so * tanhf(creg));
        }
        __syncthreads();   // bar4: all sc1 h stores drained (vmcnt 0)

        // ---- publish progress ----
        if (tid == 0)
            __hip_atomic_store(myflag, s, __ATOMIC_RELAXED, __HIP_MEMORY_SCOPE_AGENT);
    }
}

__global__ void fc_kernel(const float* __restrict__ ws, const float* __restrict__ Wfc,
                          const float* __restrict__ bfc, float* __restrict__ out)
{
    // final h of layer2 written at s=513 -> parity 513&3 = 1 -> hbuf[1][2]
    const float* h2 = ws + OFF_HBUF + (size_t)(1 * 3 + 2) * Bsz * Hh;
    int b = threadIdx.x;   // 256 threads
    float a0 = bfc[0], a1 = bfc[1], a2 = bfc[2];
    for (int k = 0; k < 128; k++) {
        float h = h2[b * 128 + k];
        a0 += h * Wfc[0 * 128 + k];
        a1 += h * Wfc[1 * 128 + k];
        a2 += h * Wfc[2 * 128 + k];
    }
    out[b * 3 + 0] = a0;
    out[b * 3 + 1] = a1;
    out[b * 3 + 2] = a2;
}

extern "C" void kernel_launch(void* const* d_in, const int* in_sizes, int n_in,
                              void* d_out, int out_size, void* d_ws, size_t ws_size,
                              hipStream_t stream)
{
    const float* x = (const float*)d_in[0];
    float* ws = (float*)d_ws;

    prep_kernel<<<6, 256, 0, stream>>>(
        (const float*)d_in[1],  (const float*)d_in[2],  (const float*)d_in[3],  (const float*)d_in[4],
        (const float*)d_in[5],  (const float*)d_in[6],  (const float*)d_in[7],  (const float*)d_in[8],
        (const float*)d_in[9],  (const float*)d_in[10], (const float*)d_in[11], (const float*)d_in[12],
        ws);

    // cooperative launch solely for the co-residency guarantee (no grid.sync inside)
    void* args[2] = { (void*)&x, (void*)&ws };
    hipLaunchCooperativeKernel((void*)lstm_kernel, dim3(192), dim3(512), args, 0, stream);

    fc_kernel<<<1, 256, 0, stream>>>(ws, (const float*)d_in[13], (const float*)d_in[14], (float*)d_out);
}

// Round 7
// 3167.511 us; speedup vs baseline: 5.4022x; 1.0216x over previous
//
#include <hip/hip_runtime.h>

#define Bsz 256
#define Tt  512
#define Hh  128

// ws layout (floats):
//   Wt_ih [3][128][512]      k-major plain input weights (zero-filled k>=Kin)
//   Wt_hh [3][128][512]      k-major plain recurrent weights
//   bias  [3][512]           bih + bhh
//   hbuf  u64[4][3][256][128] 4-deep hidden states, (seq<<32)|bits(h)  (sc1 path)
//   flags [3][16][4] x 32    staging-progress flags (anti-dep only), 128B apart
#define OFF_WTHH 196608            // 3*128*512
#define OFF_BIAS 393216            // 2*196608
#define OFF_HBUF 394752            // + 3*512   (u64 array = 786432 floats)
#define OFF_FLAG 1181184           // + 786432
#define FLAG_N   6144              // 192 flags * 32 ints (128B stride)
// total used: 1187328 floats = 4.75 MB

// swizzled A-tile column: k -> (k>>3)*12 + (k&7); 8-float k-groups at 48 B stride
// -> 16 wave-distinct addrs, 2-way max bank aliasing (free), 16B-aligned b128 reads.
#define SKG(k) ((((k) >> 3) * 12) + ((k) & 7))

typedef unsigned long long u64;
typedef unsigned int u32;

// ---- MALL-coherent (sc0 sc1 per-access) relaxed agent-scope atomics ----
__device__ __forceinline__ void st_h_agent(u64* p, float v, u32 seq) {
    u64 u = ((u64)seq << 32) | (u64)__float_as_uint(v);
    __hip_atomic_store(p, u, __ATOMIC_RELAXED, __HIP_MEMORY_SCOPE_AGENT);
}
__device__ __forceinline__ u64 ld_u64_agent(const u64* p) {
    return __hip_atomic_load(p, __ATOMIC_RELAXED, __HIP_MEMORY_SCOPE_AGENT);
}

// stage 4 consecutive (val,seq) pairs; spin until all carry seq==exp.
// The data IS the ready-signal: no flag round trip on the critical cycle.
__device__ __forceinline__ float4 stage4(const u64* __restrict__ src, u32 exp) {
    u64 a, b, c, d;
    for (;;) {
        a = ld_u64_agent(src + 0);
        b = ld_u64_agent(src + 1);
        c = ld_u64_agent(src + 2);
        d = ld_u64_agent(src + 3);
        if ((u32)(a >> 32) == exp && (u32)(b >> 32) == exp &&
            (u32)(c >> 32) == exp && (u32)(d >> 32) == exp) break;
    }
    return make_float4(__uint_as_float((u32)a), __uint_as_float((u32)b),
                       __uint_as_float((u32)c), __uint_as_float((u32)d));
}

// VALU-pipe partial-row reduction: lane 15 of each 16-lane DPP row ends with the
// sum of lanes 0..15. bound_ctrl=1 -> 0-fill.
template<int N>
__device__ __forceinline__ float row_shr_add(float v) {
    int s = __builtin_amdgcn_update_dpp(0, __float_as_int(v), 0x110 + N, 0xF, 0xF, true);
    return v + __int_as_float(s);
}
__device__ __forceinline__ float4 red16(float4 s) {
    s.x = row_shr_add<1>(s.x); s.x = row_shr_add<2>(s.x); s.x = row_shr_add<4>(s.x); s.x = row_shr_add<8>(s.x);
    s.y = row_shr_add<1>(s.y); s.y = row_shr_add<2>(s.y); s.y = row_shr_add<4>(s.y); s.y = row_shr_add<8>(s.y);
    s.z = row_shr_add<1>(s.z); s.z = row_shr_add<2>(s.z); s.z = row_shr_add<4>(s.z); s.z = row_shr_add<8>(s.z);
    s.w = row_shr_add<1>(s.w); s.w = row_shr_add<2>(s.w); s.w = row_shr_add<4>(s.w); s.w = row_shr_add<8>(s.w);
    return s;
}

#define FMA4(S, A, W) { S.x = fmaf(A, W.x, S.x); S.y = fmaf(A, W.y, S.y); \
                        S.z = fmaf(A, W.z, S.z); S.w = fmaf(A, W.w, S.w); }

__global__ void prep_kernel(const float* Wih0, const float* Whh0, const float* bih0, const float* bhh0,
                            const float* Wih1, const float* Whh1, const float* bih1, const float* bhh1,
                            const float* Wih2, const float* Whh2, const float* bih2, const float* bhh2,
                            float* ws)
{
    int gid = blockIdx.x * blockDim.x + threadIdx.x;   // 24*256 = 6144 threads
    if (gid < FLAG_N) ((int*)(ws + OFF_FLAG))[gid] = -1;      // anti-dep flags
    u64* hb = (u64*)(ws + OFF_HBUF);                          // seq init: never matches
    for (int i = gid; i < 4 * 3 * 256 * 128; i += 6144) hb[i] = 0xFFFFFFFF00000000ull;
    if (gid >= 3 * 512) return;
    int l = gid >> 9, gc = gid & 511;
    const float* Wih = (l == 0) ? Wih0 : (l == 1) ? Wih1 : Wih2;
    const float* Whh = (l == 0) ? Whh0 : (l == 1) ? Whh1 : Whh2;
    const float* bih = (l == 0) ? bih0 : (l == 1) ? bih1 : bih2;
    const float* bhh = (l == 0) ? bhh0 : (l == 1) ? bhh1 : bhh2;
    int Kin = (l == 0) ? 8 : 128;
    float* Wt_ih = ws + (size_t)l * 128 * 512;
    float* Wt_hh = ws + OFF_WTHH + (size_t)l * 128 * 512;
    float* bias  = ws + OFF_BIAS + l * 512;
    for (int k = 0; k < 128; k++) Wt_ih[k * 512 + gc] = (k < Kin) ? Wih[gc * Kin + k] : 0.f;
    for (int k = 0; k < 128; k++) Wt_hh[k * 512 + gc] = Whh[gc * 128 + k];
    bias[gc] = bih[gc] + bhh[gc];
}

// Persistent kernel, 192 blocks x 512 threads (8 waves -> 2 waves/SIMD).
// block = (layer, rtile, hctile); software wavefront t = s - layer.
// Readiness travels IN the h data (seq-tagged u64); flags only guard the depth-4
// buffer anti-dependence (target s-3, checked overlapped at slot start).
// 2 barriers per slot: barA (staging done) and barB (sG ready).
__global__ __launch_bounds__(512, 2) void lstm_kernel(const float* __restrict__ x,
                                                      float* __restrict__ ws)
{
    const float* __restrict__ bias = ws + OFF_BIAS;
    u64* __restrict__ hbuf = (u64*)(ws + OFF_HBUF);
    int* __restrict__ fl = (int*)(ws + OFF_FLAG);

    const int layer = blockIdx.x >> 6;
    const int tile  = blockIdx.x & 63;
    const int rt  = tile & 15;
    const int hct = tile >> 4;
    const int r0  = rt << 4;            // batch rows [r0, r0+16)
    const int hc0 = hct << 5;           // hidden cols [hc0, hc0+32)
    const int tid = threadIdx.x;

    __shared__ float sAin[16][192];
    __shared__ float sArec[16][192];
    __shared__ float sG[16][132];

    // zero-fill sAin (layer0 reads k>=8 against zero weights; must not be garbage)
    for (int i = tid; i < 16 * 192; i += 512) ((float*)sAin)[i] = 0.f;

    // ---- anti-dep pollers: consumers of my slot s-4 data must have staged s-3 ----
    // tid 0..3: own-layer siblings (recurrent readers); tid 4..7: downstream layer.
    int* adflag = nullptr;
    if (tid < 4)                    adflag = fl + ((layer * 16 + rt) * 4 + tid) * 32;
    else if (tid < 8 && layer < 2)  adflag = fl + (((layer + 1) * 16 + rt) * 4 + (tid - 4)) * 32;
    int* myflag = fl + ((layer * 16 + rt) * 4 + hct) * 32;

    // ---- thread tile ----
    const int kg = tid & 15;               // k-group (DPP-row lane 0..15)
    const int rg = (tid >> 4) & 1;         // row half: rows rg*8 .. rg*8+7
    const int cg = tid >> 5;               // col-group 0..15
    const int cbase = cg << 3;             // block-local col 0..120 (8 cols, same gate)
    const int gcb = ((cbase >> 5) << 7) + hc0 + (cbase & 31);   // global gate col
    const int ka = kg * 12;                // swizzled A base for this k-slice

    // ---- load weights into registers (once): 32 float4 = 128 VGPR ----
    const float* Wl_ih = ws + (size_t)layer * 65536;
    const float* Wl_hh = ws + OFF_WTHH + (size_t)layer * 65536;
    float4 wihA[8], wihB[8], whhA[8], whhB[8];
#pragma unroll
    for (int kk = 0; kk < 8; kk++) {
        int k = kg * 8 + kk;
        wihA[kk] = *(const float4*)&Wl_ih[(size_t)k * 512 + gcb];
        wihB[kk] = *(const float4*)&Wl_ih[(size_t)k * 512 + gcb + 4];
        whhA[kk] = *(const float4*)&Wl_hh[(size_t)k * 512 + gcb];
        whhB[kk] = *(const float4*)&Wl_hh[(size_t)k * 512 + gcb + 4];
    }
    float4 bias4a = *(const float4*)&bias[layer * 512 + gcb];
    float4 bias4b = *(const float4*)&bias[layer * 512 + gcb + 4];
    if (kg != 15) {   // bias added exactly once per col (at the reduction root lane)
        bias4a = make_float4(0.f, 0.f, 0.f, 0.f);
        bias4b = make_float4(0.f, 0.f, 0.f, 0.f);
    }

    // staging coords: 32 threads/row x 4 floats
    const int sr = tid >> 5;               // 0..15
    const int sk = (tid & 31) << 2;        // 0,4,...,124
    const int skc = SKG(sk);

    // cell-update coords: 1 cell/thread
    const int ur = tid >> 5, uc = tid & 31;
    float creg = 0.f;

    __syncthreads();   // sAin zero-fill visible

    for (int t = 0; t < Tt; ++t) {
        const int s = t + layer;
        const int prev = (s - 1) & 3, cur = s & 3;   // depth-4 buffering
        const u32 expseq = (u32)(s - 1);

        // ---- anti-dep (depth-4 slack: target s-3; flags init -1 auto-pass early) ----
        if (adflag != nullptr) {
            const int target = s - 3;
            while (__hip_atomic_load(adflag, __ATOMIC_RELAXED, __HIP_MEMORY_SCOPE_AGENT) < target)
                ;
        }

        // ---- stage A tiles into LDS; the seq tags ARE the ready-signal ----
        if (layer == 0) {
            if (tid < 128) {
                int r = tid >> 3, i = tid & 7;
                sAin[r][i] = x[((size_t)(r0 + r) * Tt + t) * 8 + i];
            }
        } else {
            const u64* src = hbuf + ((size_t)prev * 3 + (layer - 1)) * Bsz * Hh
                           + (size_t)(r0 + sr) * Hh + sk;
            *(float4*)&sAin[sr][skc] = stage4(src, expseq);
        }
        if (t > 0) {
            const u64* src = hbuf + ((size_t)prev * 3 + layer) * Bsz * Hh
                           + (size_t)(r0 + sr) * Hh + sk;
            *(float4*)&sArec[sr][skc] = stage4(src, expseq);
        }
        __syncthreads();   // barA: staging done (also orders anti-dep poll before stores)

        // publish "staged slot s" (earliest legal point: my reads of s-1 are complete)
        if (tid == 0)
            __hip_atomic_store(myflag, s, __ATOMIC_RELAXED, __HIP_MEMORY_SCOPE_AGENT);

        // ---- GEMM: register weights x LDS A-slices (8 rows x 8 cols / thread) ----
#pragma unroll
        for (int j = 0; j < 8; j++) {
            const int r = rg * 8 + j;
            float4 acc0 = bias4a, acc1 = bias4b;
            {
                float4 a0 = *(const float4*)&sAin[r][ka];
                float4 a1 = *(const float4*)&sAin[r][ka + 4];
                FMA4(acc0, a0.x, wihA[0]); FMA4(acc1, a0.x, wihB[0]);
                FMA4(acc0, a0.y, wihA[1]); FMA4(acc1, a0.y, wihB[1]);
                FMA4(acc0, a0.z, wihA[2]); FMA4(acc1, a0.z, wihB[2]);
                FMA4(acc0, a0.w, wihA[3]); FMA4(acc1, a0.w, wihB[3]);
                FMA4(acc0, a1.x, wihA[4]); FMA4(acc1, a1.x, wihB[4]);
                FMA4(acc0, a1.y, wihA[5]); FMA4(acc1, a1.y, wihB[5]);
                FMA4(acc0, a1.z, wihA[6]); FMA4(acc1, a1.z, wihB[6]);
                FMA4(acc0, a1.w, wihA[7]); FMA4(acc1, a1.w, wihB[7]);
            }
            if (t > 0) {
                float4 b0 = *(const float4*)&sArec[r][ka];
                float4 b1 = *(const float4*)&sArec[r][ka + 4];
                FMA4(acc0, b0.x, whhA[0]); FMA4(acc1, b0.x, whhB[0]);
                FMA4(acc0, b0.y, whhA[1]); FMA4(acc1, b0.y, whhB[1]);
                FMA4(acc0, b0.z, whhA[2]); FMA4(acc1, b0.z, whhB[2]);
                FMA4(acc0, b0.w, whhA[3]); FMA4(acc1, b0.w, whhB[3]);
                FMA4(acc0, b1.x, whhA[4]); FMA4(acc1, b1.x, whhB[4]);
                FMA4(acc0, b1.y, whhA[5]); FMA4(acc1, b1.y, whhB[5]);
                FMA4(acc0, b1.z, whhA[6]); FMA4(acc1, b1.z, whhB[6]);
                FMA4(acc0, b1.w, whhA[7]); FMA4(acc1, b1.w, whhB[7]);
            }
            acc0 = red16(acc0);            // lane kg==15: full sum + bias
            acc1 = red16(acc1);
            if (kg == 15) {
                *(float4*)&sG[r][cbase]     = acc0;
                *(float4*)&sG[r][cbase + 4] = acc1;
            }
        }
        __syncthreads();   // barB: sG visible

        // ---- LSTM cell update: 1 cell/thread; store (h,seq) -- the signal itself ----
        {
            float gi = sG[ur][uc],      gf = sG[ur][32 + uc];
            float gg = sG[ur][64 + uc], go = sG[ur][96 + uc];
            float si = 1.f / (1.f + __expf(-gi));
            float sf = 1.f / (1.f + __expf(-gf));
            float so = 1.f / (1.f + __expf(-go));
            creg = sf * creg + si * tanhf(gg);
            u64* dst = hbuf + ((size_t)cur * 3 + layer) * Bsz * Hh
                     + (size_t)(r0 + ur) * Hh + hc0 + uc;
            st_h_agent(dst, so * tanhf(creg), (u32)s);
        }
        // no barrier: next-slot staging conflicts only with GEMM reads (ended at barB)
        // and cell's sG reads (ordered before next GEMM by next barA).
    }
}

__global__ void fc_kernel(const float* __restrict__ ws, const float* __restrict__ Wfc,
                          const float* __restrict__ bfc, float* __restrict__ out)
{
    // final h of layer2 written at s=513 -> 513&3 = 1 -> hbuf[1][2]
    const u64* h2 = (const u64*)(ws + OFF_HBUF) + (size_t)(1 * 3 + 2) * Bsz * Hh;
    int b = threadIdx.x;   // 256 threads
    float a0 = bfc[0], a1 = bfc[1], a2 = bfc[2];
    for (int k = 0; k < 128; k++) {
        float h = __uint_as_float((u32)h2[b * 128 + k]);
        a0 += h * Wfc[0 * 128 + k];
        a1 += h * Wfc[1 * 128 + k];
        a2 += h * Wfc[2 * 128 + k];
    }
    out[b * 3 + 0] = a0;
    out[b * 3 + 1] = a1;
    out[b * 3 + 2] = a2;
}

extern "C" void kernel_launch(void* const* d_in, const int* in_sizes, int n_in,
                              void* d_out, int out_size, void* d_ws, size_t ws_size,
                              hipStream_t stream)
{
    const float* x = (const float*)d_in[0];
    float* ws = (float*)d_ws;

    prep_kernel<<<24, 256, 0, stream>>>(
        (const float*)d_in[1],  (const float*)d_in[2],  (const float*)d_in[3],  (const float*)d_in[4],
        (const float*)d_in[5],  (const float*)d_in[6],  (const float*)d_in[7],  (const float*)d_in[8],
        (const float*)d_in[9],  (const float*)d_in[10], (const float*)d_in[11], (const float*)d_in[12],
        ws);

    // cooperative launch solely for the co-residency guarantee (no grid.sync inside)
    void* args[2] = { (void*)&x, (void*)&ws };
    hipLaunchCooperativeKernel((void*)lstm_kernel, dim3(192), dim3(512), args, 0, stream);

    fc_kernel<<<1, 256, 0, stream>>>(ws, (const float*)d_in[13], (const float*)d_in[14], (float*)d_out);
}